// Round 7
// baseline (556.280 us; speedup 1.0000x reference)
//
#include <hip/hip_runtime.h>
#include <math.h>

#define B_ 128
#define T_ 512
#define C_ 21
#define L_ 63
#define D_ 512
#define H_ 8
#define DH_ 64
#define MODES_ 31
#define FF_ 2048
#define P_ 96
#define KMA 25
#define PAD 12
#define NOUT (P_*C_)      /* 2016 */
#define KHEAD (L_*D_)     /* 32256 */
#define ML (B_*L_)        /* 8064 rows */

typedef __attribute__((ext_vector_type(8))) short short8;
typedef __attribute__((ext_vector_type(4))) float f32x4;

__device__ __forceinline__ unsigned short f2b(float f) {
    union { float f; unsigned u; } v; v.f = f;
    unsigned r = v.u + 0x7FFFu + ((v.u >> 16) & 1u);
    return (unsigned short)(r >> 16);
}
__device__ __forceinline__ float b2f(unsigned short u) {
    union { unsigned u; float f; } v; v.u = ((unsigned)u) << 16;
    return v.f;
}
__device__ __forceinline__ void gld_lds16(const void* g, void* l) {
    __builtin_amdgcn_global_load_lds(
        (const __attribute__((address_space(1))) unsigned int*)g,
        (__attribute__((address_space(3))) unsigned int*)l, 16, 0, 0);
}

// ============ prep: all weight conversions + pad + DFT tables, one kernel ============
__global__ void prep_k(const float* __restrict__ Wq, const float* __restrict__ Wo,
                       const float* __restrict__ c1, const float* __restrict__ c2,
                       unsigned short* __restrict__ WqB, unsigned short* __restrict__ WoB,
                       unsigned short* __restrict__ c1B, unsigned short* __restrict__ c2B,
                       const float* __restrict__ pW, unsigned short* __restrict__ pWB,
                       float* __restrict__ cosT, float* __restrict__ sinT) {
    int i = blockIdx.x * 256 + threadIdx.x;
    if (i < 262144) {
        const float* src = (i < 131072) ? Wq : Wo;
        unsigned short* dst = (i < 131072) ? WqB : WoB;
        int j = i & 131071;
        float4 v = ((const float4*)src)[j];
        uint2 p; p.x = (unsigned)f2b(v.x) | ((unsigned)f2b(v.y) << 16);
        p.y = (unsigned)f2b(v.z) | ((unsigned)f2b(v.w) << 16);
        ((uint2*)dst)[j] = p;
    } else if (i < 1310720) {
        int j = i - 262144;
        const float* src = (j < 524288) ? c1 : c2;
        unsigned short* dst = (j < 524288) ? c1B : c2B;
        j &= 524287;
        float4 v = ((const float4*)src)[j];
        uint2 p; p.x = (unsigned)f2b(v.x) | ((unsigned)f2b(v.y) << 16);
        p.y = (unsigned)f2b(v.z) | ((unsigned)f2b(v.w) << 16);
        ((uint2*)dst)[j] = p;
    } else if (i < 1359872) {
        int j = i - 1310720;
        int row = j / 96, c4 = j % 96;
        uint2 p; p.x = 0; p.y = 0;
        if (c4 < 84) {
            float4 v = *(const float4*)(pW + (size_t)row * 336 + c4 * 4);
            p.x = (unsigned)f2b(v.x) | ((unsigned)f2b(v.y) << 16);
            p.y = (unsigned)f2b(v.z) | ((unsigned)f2b(v.w) << 16);
        }
        ((uint2*)pWB)[j] = p;
    } else if (i < 1361888) {
        int j = i - 1359872;
        int m = j / 63, l = j % 63;
        if (m >= MODES_) { cosT[j] = 0.f; sinT[j] = 0.f; }
        else {
            int r = (m * l) % 63;
            double a = 6.283185307179586476925286766559 * (double)r / 63.0;
            cosT[j] = (float)cos(a); sinT[j] = (float)sin(a);
        }
    }
}

// ============ series_decomp on input, rolling window, bf16 outputs ============
__global__ void decomp_input_k(const float* __restrict__ x,
                               unsigned short* __restrict__ seasB,
                               unsigned short* __restrict__ trendB) {
    int idx = blockIdx.x * 256 + threadIdx.x;
    if (idx >= B_ * C_ * 16) return;
    int tc = idx & 15; int rc = idx >> 4; int c = rc % C_; int b = rc / C_;
    const float* xb = x + (size_t)b * T_ * C_ + c;
    int t0 = tc * 32;
    float sum = 0.f;
    #pragma unroll
    for (int i = -PAD; i <= PAD; ++i) {
        int tt = t0 + i; tt = tt < 0 ? 0 : (tt > T_-1 ? T_-1 : tt);
        sum += xb[(size_t)tt * C_];
    }
    for (int t = t0; t < t0 + 32; ++t) {
        float mean = sum * (1.f / KMA);
        float xv = xb[(size_t)t * C_];
        size_t o = ((size_t)b * T_ + t) * C_ + c;
        seasB[o]  = f2b(xv - mean);
        trendB[o] = f2b(mean);
        int add = t + 13 > T_-1 ? T_-1 : t + 13;
        int rem = t - 12 < 0 ? 0 : t - 12;
        sum += xb[(size_t)add * C_] - xb[(size_t)rem * C_];
    }
}

// ============ gather patches (bf16 -> bf16, zero-padded K 336->384) ============
__global__ void patches_k(const unsigned short* __restrict__ seasB,
                          unsigned short* __restrict__ xpB) {
    int idx = blockIdx.x * 256 + threadIdx.x;
    if (idx >= B_*L_*384) return;
    int col = idx % 384; int r = idx / 384; int n = r % L_; int b = r / L_;
    unsigned short v = 0;
    if (col < 336) {
        int c = col >> 4; int j = col & 15;
        v = seasB[((size_t)b * T_ + 8*n + j) * C_ + c];
    }
    xpB[idx] = v;
}

// ============ trend head as MFMA GEMM: M=2688 (b,c), N=96 (p), K=512 (t) ============
__global__ __launch_bounds__(256) void trend_mfma(
    const unsigned short* __restrict__ trendB, const float* __restrict__ tW,
    const float* __restrict__ tb, const float* __restrict__ hb,
    float* __restrict__ outT)
{
    __shared__ unsigned short Asl[64*32];
    __shared__ unsigned short Wsl[96*32];
    int bm = blockIdx.x;
    int t = threadIdx.x, wave = t >> 6, lane = t & 63;
    int wr = wave >> 1, wc = wave & 1, g2 = lane >> 4, rl = lane & 15;
    f32x4 acc[2][3] = {};
    int ar = t >> 2, aslot = t & 3;
    int rowg = bm*64 + ar; int ab = rowg / 21, ac = rowg % 21;
    for (int k0 = 0; k0 < 512; k0 += 32) {
        __syncthreads();
        {
            unsigned short vals[8];
            int kb = k0 + aslot*8;
            #pragma unroll
            for (int j = 0; j < 8; ++j)
                vals[j] = trendB[((size_t)ab * T_ + kb + j) * C_ + ac];
            int phys = aslot ^ ((ar>>1)&3);
            *(uint4*)&Asl[ar*32 + phys*8] = *(const uint4*)vals;
        }
        #pragma unroll
        for (int i = 0; i < 3; ++i) {
            int idx = t + 256*i;
            int r = idx >> 3, c4 = idx & 7;
            float4 w4 = *(const float4*)(tW + (size_t)r * T_ + k0 + c4*4);
            uint2 p; p.x = (unsigned)f2b(w4.x) | ((unsigned)f2b(w4.y) << 16);
            p.y = (unsigned)f2b(w4.z) | ((unsigned)f2b(w4.w) << 16);
            *(uint2*)&Wsl[r*32 + (((c4>>1) ^ ((r>>1)&3)) << 3) + ((c4&1) << 2)] = p;
        }
        __syncthreads();
        short8 af[2], wf[3];
        #pragma unroll
        for (int m = 0; m < 2; ++m) {
            int r = wr*32 + m*16 + rl;
            af[m] = *(const short8*)&Asl[r*32 + ((g2 ^ ((r>>1)&3)) << 3)];
        }
        #pragma unroll
        for (int n = 0; n < 3; ++n) {
            int r = wc*48 + n*16 + rl;
            wf[n] = *(const short8*)&Wsl[r*32 + ((g2 ^ ((r>>1)&3)) << 3)];
        }
        #pragma unroll
        for (int m = 0; m < 2; ++m)
            #pragma unroll
            for (int n = 0; n < 3; ++n)
                acc[m][n] = __builtin_amdgcn_mfma_f32_16x16x32_bf16(af[m], wf[n], acc[m][n], 0,0,0);
    }
    #pragma unroll
    for (int n = 0; n < 3; ++n) {
        int p = wc*48 + n*16 + rl;
        float bias = tb[p];
        #pragma unroll
        for (int m = 0; m < 2; ++m)
            #pragma unroll
            for (int j = 0; j < 4; ++j) {
                int rg = bm*64 + wr*32 + m*16 + g2*4 + j;
                int b = rg / 21, c = rg % 21;
                outT[(size_t)b * NOUT + p*21 + c] = acc[m][n][j] + bias + hb[p*21 + c];
            }
    }
}

// ============ bf16 MFMA GEMM, tile 64(M)x128(N), BK=64, double-buffered (1 barrier/step) ============
__global__ __launch_bounds__(256) void gemm_mfma(
    const unsigned short* __restrict__ A,
    const unsigned short* __restrict__ W,
    const float* __restrict__ bias,
    float* __restrict__ Cf,
    unsigned short* __restrict__ Cb,
    int M, int N, int K, int act)
{
    __shared__ unsigned short Asl[2][64*64];
    __shared__ unsigned short Wsl[2][128*64];
    int bm = blockIdx.y, bn = blockIdx.x;
    int t = threadIdx.x;
    int wave = t >> 6, lane = t & 63;
    int wr = wave >> 1, wc = wave & 1;
    int g2 = lane >> 4, rl = lane & 15;
    int lr8 = lane >> 3, l7 = lane & 7;
    f32x4 acc[2][4] = {};
    const unsigned short* Ab = A + (size_t)(bm*64) * K;
    const unsigned short* Wb = W + (size_t)(bn*128) * K;

    // prologue: stage k0=0 into buffer 0
    #pragma unroll
    for (int i = 0; i < 2; ++i) {
        int seg = wave*2 + i;
        int r = seg*8 + lr8;
        int ko = (l7 ^ (r & 7)) << 3;
        gld_lds16(Ab + (size_t)r*K + ko, &Asl[0][seg*512]);
    }
    #pragma unroll
    for (int i = 0; i < 4; ++i) {
        int seg = wave*4 + i;
        int r = seg*8 + lr8;
        int ko = (l7 ^ (r & 7)) << 3;
        gld_lds16(Wb + (size_t)r*K + ko, &Wsl[0][seg*512]);
    }

    int cur = 0;
    for (int k0 = 0; k0 < K; k0 += 64, cur ^= 1) {
        __syncthreads();   // drains this wave's outstanding stage + prior reads
        if (k0 + 64 < K) {
            int kn = k0 + 64;
            #pragma unroll
            for (int i = 0; i < 2; ++i) {
                int seg = wave*2 + i;
                int r = seg*8 + lr8;
                int ko = (l7 ^ (r & 7)) << 3;
                gld_lds16(Ab + (size_t)r*K + kn + ko, &Asl[cur^1][seg*512]);
            }
            #pragma unroll
            for (int i = 0; i < 4; ++i) {
                int seg = wave*4 + i;
                int r = seg*8 + lr8;
                int ko = (l7 ^ (r & 7)) << 3;
                gld_lds16(Wb + (size_t)r*K + kn + ko, &Wsl[cur^1][seg*512]);
            }
        }
        short8 af[2][2], wf[2][4];
        #pragma unroll
        for (int sub = 0; sub < 2; ++sub) {
            #pragma unroll
            for (int m = 0; m < 2; ++m) {
                int r = wr*32 + m*16 + rl;
                af[sub][m] = *(const short8*)&Asl[cur][r*64 + (((sub*4+g2) ^ (r&7)) << 3)];
            }
            #pragma unroll
            for (int n = 0; n < 4; ++n) {
                int r = wc*64 + n*16 + rl;
                wf[sub][n] = *(const short8*)&Wsl[cur][r*64 + (((sub*4+g2) ^ (r&7)) << 3)];
            }
        }
        #pragma unroll
        for (int sub = 0; sub < 2; ++sub)
            #pragma unroll
            for (int m = 0; m < 2; ++m)
                #pragma unroll
                for (int n = 0; n < 4; ++n)
                    acc[m][n] = __builtin_amdgcn_mfma_f32_16x16x32_bf16(af[sub][m], wf[sub][n], acc[m][n], 0,0,0);
    }

    int crow0 = bm*64 + wr*32;
    int ccol0 = bn*128 + wc*64;
    #pragma unroll
    for (int n = 0; n < 4; ++n) {
        int col = ccol0 + n*16 + rl;
        float bv = bias ? bias[col] : 0.f;
        #pragma unroll
        for (int m = 0; m < 2; ++m) {
            #pragma unroll
            for (int j = 0; j < 4; ++j) {
                int row = crow0 + m*16 + g2*4 + j;
                float x = acc[m][n][j] + bv;
                if (act == 1) x = 0.5f * x * (1.f + erff(x * 0.70710678118654752f));
                size_t ix = (size_t)row * N + col;
                if (Cf) Cf[ix] = x;
                if (Cb) Cb[ix] = f2b(x);
            }
        }
    }
}

// ============ fourier stage 1: DFT, block per (b,h) ============
__global__ __launch_bounds__(256) void fourier1_k(
    const float* __restrict__ q, const float* __restrict__ cosT, const float* __restrict__ sinT,
    float* __restrict__ Xre_g, float* __restrict__ Xim_g)
{
    __shared__ float qs[63][64];
    __shared__ float ct[2016], st[2016];
    int b = blockIdx.x >> 3, h = blockIdx.x & 7;
    int t = threadIdx.x;
    for (int idx = t; idx < 1008; idx += 256) {
        int l = idx >> 4, e4 = idx & 15;
        *(float4*)&qs[l][e4*4] = *(const float4*)(q + ((size_t)(b*63 + l))*512 + h*64 + e4*4);
    }
    for (int idx = t; idx < 504; idx += 256) {
        *(float4*)&ct[idx*4] = *(const float4*)(cosT + idx*4);
        *(float4*)&st[idx*4] = *(const float4*)(sinT + idx*4);
    }
    __syncthreads();
    int mm = t & 31, g = t >> 5;
    float re[8] = {}, im[8] = {};
    for (int l = 0; l < 63; ++l) {
        float c = ct[mm*63 + l], s = st[mm*63 + l];
        #pragma unroll
        for (int j = 0; j < 8; ++j) {
            float v = qs[l][g*8 + j];
            re[j] = fmaf(v, c, re[j]);
            im[j] = fmaf(-v, s, im[j]);
        }
    }
    if (mm < MODES_) {
        size_t base = ((size_t)(h*MODES_ + mm)*128 + b)*64 + g*8;
        *(float4*)&Xre_g[base]   = *(float4*)&re[0];
        *(float4*)&Xre_g[base+4] = *(float4*)&re[4];
        *(float4*)&Xim_g[base]   = *(float4*)&im[0];
        *(float4*)&Xim_g[base+4] = *(float4*)&im[4];
    }
}

// ============ fourier stage 2: complex mode-mix via bf16 MFMA, block per (h,m) ============
__global__ __launch_bounds__(256) void fourier2_k(
    const float* __restrict__ Xre_g, const float* __restrict__ Xim_g,
    const float* __restrict__ wr, const float* __restrict__ wi,
    float* __restrict__ Ore_g, float* __restrict__ Oim_g)
{
    __shared__ unsigned short Xr[128*64], Xi[128*64];
    __shared__ unsigned short Wr[64*64], Wi[64*64], Wn[64*64];
    int h = blockIdx.x / MODES_, mm = blockIdx.x % MODES_;
    int t = threadIdx.x;
    size_t xbase = ((size_t)(h*MODES_ + mm)) * 128 * 64;
    #pragma unroll
    for (int i = 0; i < 8; ++i) {
        int idx = t + 256*i;
        int r = idx >> 4, c4 = idx & 15;
        int ad = r*64 + (((c4>>1) ^ (r&7)) << 3) + ((c4&1) << 2);
        float4 v = *(const float4*)(Xre_g + xbase + (size_t)r*64 + c4*4);
        uint2 p; p.x = (unsigned)f2b(v.x) | ((unsigned)f2b(v.y) << 16);
        p.y = (unsigned)f2b(v.z) | ((unsigned)f2b(v.w) << 16);
        *(uint2*)&Xr[ad] = p;
        v = *(const float4*)(Xim_g + xbase + (size_t)r*64 + c4*4);
        p.x = (unsigned)f2b(v.x) | ((unsigned)f2b(v.y) << 16);
        p.y = (unsigned)f2b(v.z) | ((unsigned)f2b(v.w) << 16);
        *(uint2*)&Xi[ad] = p;
    }
    #pragma unroll
    for (int i = 0; i < 2; ++i) {
        int idx = t + 256*i;
        int f = idx >> 3, oct = idx & 7;
        unsigned short wrv[8], wiv[8], wnv[8];
        #pragma unroll
        for (int j = 0; j < 8; ++j) {
            int e = oct*8 + j;
            size_t a = (((size_t)(h*64 + e))*64 + f)*MODES_ + mm;
            wrv[j] = f2b(wr[a]);
            wiv[j] = f2b(wi[a]);
            wnv[j] = wiv[j] ^ 0x8000u;
        }
        int ad = f*64 + ((oct ^ (f&7)) << 3);
        *(uint4*)&Wr[ad] = *(const uint4*)wrv;
        *(uint4*)&Wi[ad] = *(const uint4*)wiv;
        *(uint4*)&Wn[ad] = *(const uint4*)wnv;
    }
    __syncthreads();
    int wave = t >> 6, lane = t & 63;
    int wv = wave >> 1, wc = wave & 1;
    int g2 = lane >> 4, rl = lane & 15;
    f32x4 ar[4][2] = {}, ai[4][2] = {};
    #pragma unroll
    for (int sub = 0; sub < 2; ++sub) {
        short8 xr[4], xi[4], br[2], bi[2], bn[2];
        #pragma unroll
        for (int m = 0; m < 4; ++m) {
            int r = wv*64 + m*16 + rl;
            int off = r*64 + (((sub*4+g2) ^ (r&7)) << 3);
            xr[m] = *(const short8*)&Xr[off];
            xi[m] = *(const short8*)&Xi[off];
        }
        #pragma unroll
        for (int n = 0; n < 2; ++n) {
            int r = wc*32 + n*16 + rl;
            int off = r*64 + (((sub*4+g2) ^ (r&7)) << 3);
            br[n] = *(const short8*)&Wr[off];
            bi[n] = *(const short8*)&Wi[off];
            bn[n] = *(const short8*)&Wn[off];
        }
        #pragma unroll
        for (int m = 0; m < 4; ++m)
            #pragma unroll
            for (int n = 0; n < 2; ++n) {
                ar[m][n] = __builtin_amdgcn_mfma_f32_16x16x32_bf16(xr[m], br[n], ar[m][n], 0,0,0);
                ar[m][n] = __builtin_amdgcn_mfma_f32_16x16x32_bf16(xi[m], bn[n], ar[m][n], 0,0,0);
                ai[m][n] = __builtin_amdgcn_mfma_f32_16x16x32_bf16(xr[m], bi[n], ai[m][n], 0,0,0);
                ai[m][n] = __builtin_amdgcn_mfma_f32_16x16x32_bf16(xi[m], br[n], ai[m][n], 0,0,0);
            }
    }
    #pragma unroll
    for (int m = 0; m < 4; ++m)
        #pragma unroll
        for (int n = 0; n < 2; ++n)
            #pragma unroll
            for (int j = 0; j < 4; ++j) {
                int b = wv*64 + m*16 + g2*4 + j;
                int f = wc*32 + n*16 + rl;
                Ore_g[xbase + (size_t)b*64 + f] = ar[m][n][j];
                Oim_g[xbase + (size_t)b*64 + f] = ai[m][n][j];
            }
}

// ============ fourier stage 3: iDFT (drops Im(X0)), block per (b,h), bf16 out ============
__global__ __launch_bounds__(256) void fourier3_k(
    const float* __restrict__ Ore_g, const float* __restrict__ Oim_g,
    const float* __restrict__ cosT, const float* __restrict__ sinT,
    unsigned short* __restrict__ yB)
{
    __shared__ float Ore[31][64], Oim[31][64];
    __shared__ float ct[2016], st[2016];
    int b = blockIdx.x >> 3, h = blockIdx.x & 7;
    int t = threadIdx.x;
    for (int idx = t; idx < 496; idx += 256) {
        int m = idx >> 4, e4 = idx & 15;
        size_t a = ((size_t)(h*MODES_ + m)*128 + b)*64 + e4*4;
        *(float4*)&Ore[m][e4*4] = *(const float4*)(Ore_g + a);
        *(float4*)&Oim[m][e4*4] = *(const float4*)(Oim_g + a);
    }
    for (int idx = t; idx < 504; idx += 256) {
        *(float4*)&ct[idx*4] = *(const float4*)(cosT + idx*4);
        *(float4*)&st[idx*4] = *(const float4*)(sinT + idx*4);
    }
    __syncthreads();
    int f = t & 63, w = t >> 6;
    int l0 = w*16;
    float y[16];
    float r0 = Ore[0][f];
    #pragma unroll
    for (int i = 0; i < 16; ++i) y[i] = r0;
    for (int m = 1; m < MODES_; ++m) {
        float re2 = 2.f*Ore[m][f], im2 = 2.f*Oim[m][f];
        #pragma unroll
        for (int i = 0; i < 16; ++i) {
            y[i] = fmaf(re2, ct[m*63 + l0 + i], y[i]);
            y[i] = fmaf(-im2, st[m*63 + l0 + i], y[i]);
        }
    }
    int nl = (w == 3) ? 15 : 16;
    unsigned short* yo = yB + ((size_t)(b*512) + h*64 + f) * 63 + l0;
    for (int i = 0; i < nl; ++i) yo[i] = f2b(y[i] * (1.f/63.f));
}

// ============ (X+Y) - movavg(X+Y), bf16 in/out, rolling window ============
__global__ void decomp_add_k(const unsigned short* __restrict__ X,
                             const unsigned short* __restrict__ Yv,
                             unsigned short* __restrict__ outB) {
    int idx = blockIdx.x * 256 + threadIdx.x;
    if (idx >= B_*D_) return;
    int b = idx >> 9, d = idx & 511;
    const unsigned short* xp = X  + (size_t)b * L_ * D_ + d;
    const unsigned short* yp = Yv + (size_t)b * L_ * D_ + d;
    unsigned short* ob = outB + (size_t)b * L_ * D_ + d;
    #define RD(l) (b2f(xp[(size_t)(l) * D_]) + b2f(yp[(size_t)(l) * D_]))
    float sum = 13.f * RD(0);
    #pragma unroll
    for (int j = 1; j <= 12; ++j) sum += RD(j);
    for (int l = 0; l < L_; ++l) {
        float res = RD(l) - sum * (1.f / KMA);
        ob[(size_t)l * D_] = f2b(res);
        int add = l + 13 > L_-1 ? L_-1 : l + 13;
        int rem = l - 12 < 0 ? 0 : l - 12;
        sum += RD(add) - RD(rem);
    }
    #undef RD
}

// ============ fused layernorm (row) + mean-subtract (column over L), block per b ============
__global__ __launch_bounds__(256) void ln_colmean_k(
    const unsigned short* __restrict__ Xb, const float* __restrict__ g,
    const float* __restrict__ bt, unsigned short* __restrict__ outB)
{
    __shared__ unsigned short lds[63][512];
    int b = blockIdx.x;
    int w = threadIdx.x >> 6, lane = threadIdx.x & 63;
    for (int i = 0; i < 16; ++i) {
        int row = w*16 + i;
        if (row >= 63) break;
        const unsigned short* x = Xb + ((size_t)(b*63 + row))*512 + lane*8;
        uint4 raw = *(const uint4*)x;
        const unsigned short* rp = (const unsigned short*)&raw;
        float v[8]; float s = 0.f, s2 = 0.f;
        #pragma unroll
        for (int j = 0; j < 8; ++j) { v[j] = b2f(rp[j]); s += v[j]; s2 += v[j]*v[j]; }
        #pragma unroll
        for (int o = 32; o > 0; o >>= 1) { s += __shfl_down(s, o); s2 += __shfl_down(s2, o); }
        s = __shfl(s, 0); s2 = __shfl(s2, 0);
        float mu = s * (1.f/D_);
        float var = s2 * (1.f/D_) - mu*mu;
        float rs = rsqrtf(var + 1e-5f);
        unsigned short o16[8];
        #pragma unroll
        for (int j = 0; j < 8; ++j) {
            int d = lane*8 + j;
            o16[j] = f2b((v[j] - mu) * rs * g[d] + bt[d]);
        }
        *(uint4*)&lds[row][lane*8] = *(const uint4*)o16;
    }
    __syncthreads();
    #pragma unroll
    for (int i = 0; i < 2; ++i) {
        int d = threadIdx.x + 256*i;
        float s = 0.f;
        for (int l = 0; l < 63; ++l) s += b2f(lds[l][d]);
        s *= (1.f / 63.f);
        for (int l = 0; l < 63; ++l)
            outB[((size_t)(b*63 + l))*512 + d] = f2b(b2f(lds[l][d]) - s);
    }
}

// ============ head GEMM v2: barrier-free K-loop, W direct-to-register ============
// grid (42 n-tiles of 48, 12 k-chunks of 2688). 4 waves/block each owning a 672-k slice.
// W: global f32 -> regs -> bf16 (private per wave). A: global bf16 -> regs (L3-hot).
// Wave partials reduced via LDS at end; 12 k-chunk parts summed by reduce_k.
__global__ __launch_bounds__(256) void head_mfma(
    const unsigned short* __restrict__ A,
    const float* __restrict__ W,
    float* __restrict__ parts)
{
    __shared__ float red[128][48];
    int nt = blockIdx.x;       // 0..41
    int kc = blockIdx.y;       // 0..11
    int wv = threadIdx.x >> 6, lane = threadIdx.x & 63;
    int rl = lane & 15, g2 = lane >> 4;
    f32x4 acc[8][3] = {};
    const unsigned short* Ab = A + (size_t)rl * KHEAD;
    const float* Wb = W + (size_t)(nt*48 + rl) * KHEAD;
    int kbeg = kc*2688 + wv*672 + g2*8;

    for (int ks = 0; ks < 21; ++ks) {
        int k = kbeg + ks*32;
        short8 af[8];
        #pragma unroll
        for (int m = 0; m < 8; ++m)
            af[m] = *(const short8*)(Ab + (size_t)(m*16) * KHEAD + k);
        short8 wf[3];
        #pragma unroll
        for (int n = 0; n < 3; ++n) {
            float4 lo = *(const float4*)(Wb + (size_t)(n*16) * KHEAD + k);
            float4 hi = *(const float4*)(Wb + (size_t)(n*16) * KHEAD + k + 4);
            unsigned short u[8] = { f2b(lo.x), f2b(lo.y), f2b(lo.z), f2b(lo.w),
                                    f2b(hi.x), f2b(hi.y), f2b(hi.z), f2b(hi.w) };
            wf[n] = *(const short8*)u;
        }
        #pragma unroll
        for (int m = 0; m < 8; ++m)
            #pragma unroll
            for (int n = 0; n < 3; ++n)
                acc[m][n] = __builtin_amdgcn_mfma_f32_16x16x32_bf16(af[m], wf[n], acc[m][n], 0,0,0);
    }

    // reduce 4 wave-partials via LDS (turn-based)
    for (int w = 0; w < 4; ++w) {
        if (wv == w) {
            #pragma unroll
            for (int m = 0; m < 8; ++m)
                #pragma unroll
                for (int n = 0; n < 3; ++n)
                    #pragma unroll
                    for (int j = 0; j < 4; ++j) {
                        int row = m*16 + g2*4 + j, col = n*16 + rl;
                        if (w == 0) red[row][col] = acc[m][n][j];
                        else        red[row][col] += acc[m][n][j];
                    }
        }
        __syncthreads();
    }
    float* pout = parts + (size_t)kc * (B_*NOUT);
    for (int idx = threadIdx.x; idx < 128*48; idx += 256) {
        int row = idx / 48, col = idx % 48;
        pout[(size_t)row * NOUT + nt*48 + col] = red[row][col];
    }
}

// ============ out = trendout + sum of 12 parts ============
__global__ void reduce_k(const float* __restrict__ trendout, const float* __restrict__ parts,
                         float* __restrict__ out) {
    int i = blockIdx.x * 256 + threadIdx.x;
    if (i >= 64512) return;
    float4 s = ((const float4*)trendout)[i];
    for (int kc = 0; kc < 12; ++kc) {
        float4 p = ((const float4*)parts)[(size_t)kc * 64512 + i];
        s.x += p.x; s.y += p.y; s.z += p.z; s.w += p.w;
    }
    ((float4*)out)[i] = s;
}

extern "C" void kernel_launch(void* const* d_in, const int* in_sizes, int n_in,
                              void* d_out, int out_size, void* d_ws, size_t ws_size,
                              hipStream_t stream) {
    const float* x_enc   = (const float*)d_in[0];
    const float* patch_W = (const float*)d_in[4];
    const float* patch_b = (const float*)d_in[5];
    const float* Wq      = (const float*)d_in[6];
    const float* bq      = (const float*)d_in[7];
    const float* Wo      = (const float*)d_in[8];
    const float* bo      = (const float*)d_in[9];
    const float* four_wr = (const float*)d_in[10];
    const float* four_wi = (const float*)d_in[11];
    const float* c1      = (const float*)d_in[12];
    const float* c2      = (const float*)d_in[13];
    const float* gamma   = (const float*)d_in[14];
    const float* beta    = (const float*)d_in[15];
    const float* head_W  = (const float*)d_in[16];
    const float* head_b  = (const float*)d_in[17];
    const float* trend_W = (const float*)d_in[18];
    const float* trend_b = (const float*)d_in[19];
    float* out = (float*)d_out;
    float* ws  = (float*)d_ws;

    unsigned short* seasB  = (unsigned short*)ws;
    unsigned short* trendB = (unsigned short*)(ws + 688128);
    unsigned short* xpB    = (unsigned short*)(ws + 1376256);
    unsigned short* bufAb  = (unsigned short*)(ws + 2924544);
    unsigned short* tmpB16 = (unsigned short*)(ws + 4988928);
    unsigned short* tmp2   = (unsigned short*)(ws + 7053312);
    unsigned short* bufCb  = (unsigned short*)(ws + 9117696);
    float* qF    = ws + 11182080;
    float* Ore_g = qF;
    float* Oim_g = qF + 2031616;
    float* big   = ws + 15310848;
    unsigned short* hidB = (unsigned short*)big;
    float* Xre_g = big;
    float* Xim_g = big + 2031616;
    unsigned short* WqB = (unsigned short*)(ws + 23568384);
    unsigned short* WoB = (unsigned short*)(ws + 23830528);
    unsigned short* c1B = (unsigned short*)(ws + 24092672);
    unsigned short* c2B = (unsigned short*)(ws + 25141248);
    unsigned short* pWB = (unsigned short*)(ws + 26189824);
    float* cosT = ws + 26288128;
    float* sinT = ws + 26290144;
    float* trendout = ws + 26292160;
    float* parts = ws + 26550208;     // 12 * 258048 floats

    auto cdiv = [](int a, int b) { return (a + b - 1) / b; };

    prep_k<<<5321,256,0,stream>>>(Wq, Wo, c1, c2, WqB, WoB, c1B, c2B, patch_W, pWB, cosT, sinT);
    decomp_input_k<<<cdiv(B_*C_*16,256),256,0,stream>>>(x_enc, seasB, trendB);
    patches_k<<<cdiv(B_*L_*384,256),256,0,stream>>>(seasB, xpB);
    trend_mfma<<<42,256,0,stream>>>(trendB, trend_W, trend_b, head_b, trendout);

    gemm_mfma<<<dim3(4,126),256,0,stream>>>(xpB, pWB, patch_b, (float*)nullptr, bufAb, ML, 512, 384, 0);

    for (int l = 0; l < 2; ++l) {
        const unsigned short* WqB_l = WqB + (size_t)l*512*512;
        const unsigned short* WoB_l = WoB + (size_t)l*512*512;
        const unsigned short* c1B_l = c1B + (size_t)l*FF_*D_;
        const unsigned short* c2B_l = c2B + (size_t)l*D_*FF_;
        const float* bq_l = bq + (size_t)l*512;
        const float* bo_l = bo + (size_t)l*512;
        const float* wr_l = four_wr + (size_t)l*H_*DH_*DH_*MODES_;
        const float* wi_l = four_wi + (size_t)l*H_*DH_*DH_*MODES_;

        gemm_mfma<<<dim3(4,126),256,0,stream>>>(bufAb, WqB_l, bq_l, qF, (unsigned short*)nullptr, ML, 512, 512, 0);
        fourier1_k<<<B_*H_,256,0,stream>>>(qF, cosT, sinT, Xre_g, Xim_g);
        fourier2_k<<<H_*MODES_,256,0,stream>>>(Xre_g, Xim_g, wr_l, wi_l, Ore_g, Oim_g);
        fourier3_k<<<B_*H_,256,0,stream>>>(Ore_g, Oim_g, cosT, sinT, tmpB16);
        gemm_mfma<<<dim3(4,126),256,0,stream>>>(tmpB16, WoB_l, bo_l, (float*)nullptr, tmp2, ML, 512, 512, 0);
        decomp_add_k<<<cdiv(B_*D_,256),256,0,stream>>>(bufAb, tmp2, bufCb);
        gemm_mfma<<<dim3(16,126),256,0,stream>>>(bufCb, c1B_l, (const float*)nullptr, (float*)nullptr, hidB, ML, FF_, 512, 1);
        gemm_mfma<<<dim3(4,126),256,0,stream>>>(hidB, c2B_l, (const float*)nullptr, (float*)nullptr, tmp2, ML, 512, FF_, 0);
        decomp_add_k<<<cdiv(B_*D_,256),256,0,stream>>>(bufCb, tmp2, bufAb);
    }

    ln_colmean_k<<<B_,256,0,stream>>>(bufAb, gamma, beta, tmpB16);
    head_mfma<<<dim3(42,12),256,0,stream>>>(tmpB16, head_W, parts);
    reduce_k<<<cdiv(64512,256),256,0,stream>>>(trendout, parts, out);
}

// Round 8
// 556.123 us; speedup vs baseline: 1.0003x; 1.0003x over previous
//
#include <hip/hip_runtime.h>
#include <math.h>

#define B_ 128
#define T_ 512
#define C_ 21
#define L_ 63
#define D_ 512
#define H_ 8
#define DH_ 64
#define MODES_ 31
#define FF_ 2048
#define P_ 96
#define KMA 25
#define PAD 12
#define NOUT (P_*C_)      /* 2016 */
#define KHEAD (L_*D_)     /* 32256 */
#define ML (B_*L_)        /* 8064 rows */

typedef __attribute__((ext_vector_type(8))) short short8;
typedef __attribute__((ext_vector_type(4))) float f32x4;

__device__ __forceinline__ unsigned short f2b(float f) {
    union { float f; unsigned u; } v; v.f = f;
    unsigned r = v.u + 0x7FFFu + ((v.u >> 16) & 1u);
    return (unsigned short)(r >> 16);
}
__device__ __forceinline__ float b2f(unsigned short u) {
    union { unsigned u; float f; } v; v.u = ((unsigned)u) << 16;
    return v.f;
}
__device__ __forceinline__ void gld_lds16(const void* g, void* l) {
    __builtin_amdgcn_global_load_lds(
        (const __attribute__((address_space(1))) unsigned int*)g,
        (__attribute__((address_space(3))) unsigned int*)l, 16, 0, 0);
}

// ============ prep: all weight conversions + pad + DFT tables, one kernel ============
__global__ void prep_k(const float* __restrict__ Wq, const float* __restrict__ Wo,
                       const float* __restrict__ c1, const float* __restrict__ c2,
                       unsigned short* __restrict__ WqB, unsigned short* __restrict__ WoB,
                       unsigned short* __restrict__ c1B, unsigned short* __restrict__ c2B,
                       const float* __restrict__ pW, unsigned short* __restrict__ pWB,
                       float* __restrict__ cosT, float* __restrict__ sinT) {
    int i = blockIdx.x * 256 + threadIdx.x;
    if (i < 262144) {
        const float* src = (i < 131072) ? Wq : Wo;
        unsigned short* dst = (i < 131072) ? WqB : WoB;
        int j = i & 131071;
        float4 v = ((const float4*)src)[j];
        uint2 p; p.x = (unsigned)f2b(v.x) | ((unsigned)f2b(v.y) << 16);
        p.y = (unsigned)f2b(v.z) | ((unsigned)f2b(v.w) << 16);
        ((uint2*)dst)[j] = p;
    } else if (i < 1310720) {
        int j = i - 262144;
        const float* src = (j < 524288) ? c1 : c2;
        unsigned short* dst = (j < 524288) ? c1B : c2B;
        j &= 524287;
        float4 v = ((const float4*)src)[j];
        uint2 p; p.x = (unsigned)f2b(v.x) | ((unsigned)f2b(v.y) << 16);
        p.y = (unsigned)f2b(v.z) | ((unsigned)f2b(v.w) << 16);
        ((uint2*)dst)[j] = p;
    } else if (i < 1359872) {
        int j = i - 1310720;
        int row = j / 96, c4 = j % 96;
        uint2 p; p.x = 0; p.y = 0;
        if (c4 < 84) {
            float4 v = *(const float4*)(pW + (size_t)row * 336 + c4 * 4);
            p.x = (unsigned)f2b(v.x) | ((unsigned)f2b(v.y) << 16);
            p.y = (unsigned)f2b(v.z) | ((unsigned)f2b(v.w) << 16);
        }
        ((uint2*)pWB)[j] = p;
    } else if (i < 1361888) {
        int j = i - 1359872;
        int m = j / 63, l = j % 63;
        if (m >= MODES_) { cosT[j] = 0.f; sinT[j] = 0.f; }
        else {
            int r = (m * l) % 63;
            double a = 6.283185307179586476925286766559 * (double)r / 63.0;
            cosT[j] = (float)cos(a); sinT[j] = (float)sin(a);
        }
    }
}

// ============ series_decomp on input, rolling window, bf16 outputs ============
__global__ void decomp_input_k(const float* __restrict__ x,
                               unsigned short* __restrict__ seasB,
                               unsigned short* __restrict__ trendB) {
    int idx = blockIdx.x * 256 + threadIdx.x;
    if (idx >= B_ * C_ * 16) return;
    int tc = idx & 15; int rc = idx >> 4; int c = rc % C_; int b = rc / C_;
    const float* xb = x + (size_t)b * T_ * C_ + c;
    int t0 = tc * 32;
    float sum = 0.f;
    #pragma unroll
    for (int i = -PAD; i <= PAD; ++i) {
        int tt = t0 + i; tt = tt < 0 ? 0 : (tt > T_-1 ? T_-1 : tt);
        sum += xb[(size_t)tt * C_];
    }
    for (int t = t0; t < t0 + 32; ++t) {
        float mean = sum * (1.f / KMA);
        float xv = xb[(size_t)t * C_];
        size_t o = ((size_t)b * T_ + t) * C_ + c;
        seasB[o]  = f2b(xv - mean);
        trendB[o] = f2b(mean);
        int add = t + 13 > T_-1 ? T_-1 : t + 13;
        int rem = t - 12 < 0 ? 0 : t - 12;
        sum += xb[(size_t)add * C_] - xb[(size_t)rem * C_];
    }
}

// ============ gather patches (bf16 -> bf16, zero-padded K 336->384) ============
__global__ void patches_k(const unsigned short* __restrict__ seasB,
                          unsigned short* __restrict__ xpB) {
    int idx = blockIdx.x * 256 + threadIdx.x;
    if (idx >= B_*L_*384) return;
    int col = idx % 384; int r = idx / 384; int n = r % L_; int b = r / L_;
    unsigned short v = 0;
    if (col < 336) {
        int c = col >> 4; int j = col & 15;
        v = seasB[((size_t)b * T_ + 8*n + j) * C_ + c];
    }
    xpB[idx] = v;
}

// ============ trend head as MFMA GEMM: M=2688 (b,c), N=96 (p), K=512 (t) ============
__global__ __launch_bounds__(256) void trend_mfma(
    const unsigned short* __restrict__ trendB, const float* __restrict__ tW,
    const float* __restrict__ tb, const float* __restrict__ hb,
    float* __restrict__ outT)
{
    __shared__ unsigned short Asl[64*32];
    __shared__ unsigned short Wsl[96*32];
    int bm = blockIdx.x;
    int t = threadIdx.x, wave = t >> 6, lane = t & 63;
    int wr = wave >> 1, wc = wave & 1, g2 = lane >> 4, rl = lane & 15;
    f32x4 acc[2][3] = {};
    int ar = t >> 2, aslot = t & 3;
    int rowg = bm*64 + ar; int ab = rowg / 21, ac = rowg % 21;
    for (int k0 = 0; k0 < 512; k0 += 32) {
        __syncthreads();
        {
            unsigned short vals[8];
            int kb = k0 + aslot*8;
            #pragma unroll
            for (int j = 0; j < 8; ++j)
                vals[j] = trendB[((size_t)ab * T_ + kb + j) * C_ + ac];
            int phys = aslot ^ ((ar>>1)&3);
            *(uint4*)&Asl[ar*32 + phys*8] = *(const uint4*)vals;
        }
        #pragma unroll
        for (int i = 0; i < 3; ++i) {
            int idx = t + 256*i;
            int r = idx >> 3, c4 = idx & 7;
            float4 w4 = *(const float4*)(tW + (size_t)r * T_ + k0 + c4*4);
            uint2 p; p.x = (unsigned)f2b(w4.x) | ((unsigned)f2b(w4.y) << 16);
            p.y = (unsigned)f2b(w4.z) | ((unsigned)f2b(w4.w) << 16);
            *(uint2*)&Wsl[r*32 + (((c4>>1) ^ ((r>>1)&3)) << 3) + ((c4&1) << 2)] = p;
        }
        __syncthreads();
        short8 af[2], wf[3];
        #pragma unroll
        for (int m = 0; m < 2; ++m) {
            int r = wr*32 + m*16 + rl;
            af[m] = *(const short8*)&Asl[r*32 + ((g2 ^ ((r>>1)&3)) << 3)];
        }
        #pragma unroll
        for (int n = 0; n < 3; ++n) {
            int r = wc*48 + n*16 + rl;
            wf[n] = *(const short8*)&Wsl[r*32 + ((g2 ^ ((r>>1)&3)) << 3)];
        }
        #pragma unroll
        for (int m = 0; m < 2; ++m)
            #pragma unroll
            for (int n = 0; n < 3; ++n)
                acc[m][n] = __builtin_amdgcn_mfma_f32_16x16x32_bf16(af[m], wf[n], acc[m][n], 0,0,0);
    }
    #pragma unroll
    for (int n = 0; n < 3; ++n) {
        int p = wc*48 + n*16 + rl;
        float bias = tb[p];
        #pragma unroll
        for (int m = 0; m < 2; ++m)
            #pragma unroll
            for (int j = 0; j < 4; ++j) {
                int rg = bm*64 + wr*32 + m*16 + g2*4 + j;
                int b = rg / 21, c = rg % 21;
                outT[(size_t)b * NOUT + p*21 + c] = acc[m][n][j] + bias + hb[p*21 + c];
            }
    }
}

// ============ bf16 MFMA GEMM, tile 64(M)x128(N), BK=64, double-buffered (1 barrier/step) ============
__global__ __launch_bounds__(256) void gemm_mfma(
    const unsigned short* __restrict__ A,
    const unsigned short* __restrict__ W,
    const float* __restrict__ bias,
    float* __restrict__ Cf,
    unsigned short* __restrict__ Cb,
    int M, int N, int K, int act)
{
    __shared__ unsigned short Asl[2][64*64];
    __shared__ unsigned short Wsl[2][128*64];
    int bm = blockIdx.y, bn = blockIdx.x;
    int t = threadIdx.x;
    int wave = t >> 6, lane = t & 63;
    int wr = wave >> 1, wc = wave & 1;
    int g2 = lane >> 4, rl = lane & 15;
    int lr8 = lane >> 3, l7 = lane & 7;
    f32x4 acc[2][4] = {};
    const unsigned short* Ab = A + (size_t)(bm*64) * K;
    const unsigned short* Wb = W + (size_t)(bn*128) * K;

    // prologue: stage k0=0 into buffer 0
    #pragma unroll
    for (int i = 0; i < 2; ++i) {
        int seg = wave*2 + i;
        int r = seg*8 + lr8;
        int ko = (l7 ^ (r & 7)) << 3;
        gld_lds16(Ab + (size_t)r*K + ko, &Asl[0][seg*512]);
    }
    #pragma unroll
    for (int i = 0; i < 4; ++i) {
        int seg = wave*4 + i;
        int r = seg*8 + lr8;
        int ko = (l7 ^ (r & 7)) << 3;
        gld_lds16(Wb + (size_t)r*K + ko, &Wsl[0][seg*512]);
    }

    int cur = 0;
    for (int k0 = 0; k0 < K; k0 += 64, cur ^= 1) {
        __syncthreads();   // drains this wave's outstanding stage + prior reads
        if (k0 + 64 < K) {
            int kn = k0 + 64;
            #pragma unroll
            for (int i = 0; i < 2; ++i) {
                int seg = wave*2 + i;
                int r = seg*8 + lr8;
                int ko = (l7 ^ (r & 7)) << 3;
                gld_lds16(Ab + (size_t)r*K + kn + ko, &Asl[cur^1][seg*512]);
            }
            #pragma unroll
            for (int i = 0; i < 4; ++i) {
                int seg = wave*4 + i;
                int r = seg*8 + lr8;
                int ko = (l7 ^ (r & 7)) << 3;
                gld_lds16(Wb + (size_t)r*K + kn + ko, &Wsl[cur^1][seg*512]);
            }
        }
        short8 af[2][2], wf[2][4];
        #pragma unroll
        for (int sub = 0; sub < 2; ++sub) {
            #pragma unroll
            for (int m = 0; m < 2; ++m) {
                int r = wr*32 + m*16 + rl;
                af[sub][m] = *(const short8*)&Asl[cur][r*64 + (((sub*4+g2) ^ (r&7)) << 3)];
            }
            #pragma unroll
            for (int n = 0; n < 4; ++n) {
                int r = wc*64 + n*16 + rl;
                wf[sub][n] = *(const short8*)&Wsl[cur][r*64 + (((sub*4+g2) ^ (r&7)) << 3)];
            }
        }
        #pragma unroll
        for (int sub = 0; sub < 2; ++sub)
            #pragma unroll
            for (int m = 0; m < 2; ++m)
                #pragma unroll
                for (int n = 0; n < 4; ++n)
                    acc[m][n] = __builtin_amdgcn_mfma_f32_16x16x32_bf16(af[sub][m], wf[sub][n], acc[m][n], 0,0,0);
    }

    int crow0 = bm*64 + wr*32;
    int ccol0 = bn*128 + wc*64;
    #pragma unroll
    for (int n = 0; n < 4; ++n) {
        int col = ccol0 + n*16 + rl;
        float bv = bias ? bias[col] : 0.f;
        #pragma unroll
        for (int m = 0; m < 2; ++m) {
            #pragma unroll
            for (int j = 0; j < 4; ++j) {
                int row = crow0 + m*16 + g2*4 + j;
                float x = acc[m][n][j] + bv;
                if (act == 1) x = 0.5f * x * (1.f + erff(x * 0.70710678118654752f));
                size_t ix = (size_t)row * N + col;
                if (Cf) Cf[ix] = x;
                if (Cb) Cb[ix] = f2b(x);
            }
        }
    }
}

// ============ fourier stage 1: DFT, block per (b,h) ============
__global__ __launch_bounds__(256) void fourier1_k(
    const float* __restrict__ q, const float* __restrict__ cosT, const float* __restrict__ sinT,
    float* __restrict__ Xre_g, float* __restrict__ Xim_g)
{
    __shared__ float qs[63][64];
    __shared__ float ct[2016], st[2016];
    int b = blockIdx.x >> 3, h = blockIdx.x & 7;
    int t = threadIdx.x;
    for (int idx = t; idx < 1008; idx += 256) {
        int l = idx >> 4, e4 = idx & 15;
        *(float4*)&qs[l][e4*4] = *(const float4*)(q + ((size_t)(b*63 + l))*512 + h*64 + e4*4);
    }
    for (int idx = t; idx < 504; idx += 256) {
        *(float4*)&ct[idx*4] = *(const float4*)(cosT + idx*4);
        *(float4*)&st[idx*4] = *(const float4*)(sinT + idx*4);
    }
    __syncthreads();
    int mm = t & 31, g = t >> 5;
    float re[8] = {}, im[8] = {};
    for (int l = 0; l < 63; ++l) {
        float c = ct[mm*63 + l], s = st[mm*63 + l];
        #pragma unroll
        for (int j = 0; j < 8; ++j) {
            float v = qs[l][g*8 + j];
            re[j] = fmaf(v, c, re[j]);
            im[j] = fmaf(-v, s, im[j]);
        }
    }
    if (mm < MODES_) {
        size_t base = ((size_t)(h*MODES_ + mm)*128 + b)*64 + g*8;
        *(float4*)&Xre_g[base]   = *(float4*)&re[0];
        *(float4*)&Xre_g[base+4] = *(float4*)&re[4];
        *(float4*)&Xim_g[base]   = *(float4*)&im[0];
        *(float4*)&Xim_g[base+4] = *(float4*)&im[4];
    }
}

// ============ fourier stage 2: complex mode-mix via bf16 MFMA, block per (h,m) ============
__global__ __launch_bounds__(256) void fourier2_k(
    const float* __restrict__ Xre_g, const float* __restrict__ Xim_g,
    const float* __restrict__ wr, const float* __restrict__ wi,
    float* __restrict__ Ore_g, float* __restrict__ Oim_g)
{
    __shared__ unsigned short Xr[128*64], Xi[128*64];
    __shared__ unsigned short Wr[64*64], Wi[64*64], Wn[64*64];
    int h = blockIdx.x / MODES_, mm = blockIdx.x % MODES_;
    int t = threadIdx.x;
    size_t xbase = ((size_t)(h*MODES_ + mm)) * 128 * 64;
    #pragma unroll
    for (int i = 0; i < 8; ++i) {
        int idx = t + 256*i;
        int r = idx >> 4, c4 = idx & 15;
        int ad = r*64 + (((c4>>1) ^ (r&7)) << 3) + ((c4&1) << 2);
        float4 v = *(const float4*)(Xre_g + xbase + (size_t)r*64 + c4*4);
        uint2 p; p.x = (unsigned)f2b(v.x) | ((unsigned)f2b(v.y) << 16);
        p.y = (unsigned)f2b(v.z) | ((unsigned)f2b(v.w) << 16);
        *(uint2*)&Xr[ad] = p;
        v = *(const float4*)(Xim_g + xbase + (size_t)r*64 + c4*4);
        p.x = (unsigned)f2b(v.x) | ((unsigned)f2b(v.y) << 16);
        p.y = (unsigned)f2b(v.z) | ((unsigned)f2b(v.w) << 16);
        *(uint2*)&Xi[ad] = p;
    }
    #pragma unroll
    for (int i = 0; i < 2; ++i) {
        int idx = t + 256*i;
        int f = idx >> 3, oct = idx & 7;
        unsigned short wrv[8], wiv[8], wnv[8];
        #pragma unroll
        for (int j = 0; j < 8; ++j) {
            int e = oct*8 + j;
            size_t a = (((size_t)(h*64 + e))*64 + f)*MODES_ + mm;
            wrv[j] = f2b(wr[a]);
            wiv[j] = f2b(wi[a]);
            wnv[j] = wiv[j] ^ 0x8000u;
        }
        int ad = f*64 + ((oct ^ (f&7)) << 3);
        *(uint4*)&Wr[ad] = *(const uint4*)wrv;
        *(uint4*)&Wi[ad] = *(const uint4*)wiv;
        *(uint4*)&Wn[ad] = *(const uint4*)wnv;
    }
    __syncthreads();
    int wave = t >> 6, lane = t & 63;
    int wv = wave >> 1, wc = wave & 1;
    int g2 = lane >> 4, rl = lane & 15;
    f32x4 ar[4][2] = {}, ai[4][2] = {};
    #pragma unroll
    for (int sub = 0; sub < 2; ++sub) {
        short8 xr[4], xi[4], br[2], bi[2], bn[2];
        #pragma unroll
        for (int m = 0; m < 4; ++m) {
            int r = wv*64 + m*16 + rl;
            int off = r*64 + (((sub*4+g2) ^ (r&7)) << 3);
            xr[m] = *(const short8*)&Xr[off];
            xi[m] = *(const short8*)&Xi[off];
        }
        #pragma unroll
        for (int n = 0; n < 2; ++n) {
            int r = wc*32 + n*16 + rl;
            int off = r*64 + (((sub*4+g2) ^ (r&7)) << 3);
            br[n] = *(const short8*)&Wr[off];
            bi[n] = *(const short8*)&Wi[off];
            bn[n] = *(const short8*)&Wn[off];
        }
        #pragma unroll
        for (int m = 0; m < 4; ++m)
            #pragma unroll
            for (int n = 0; n < 2; ++n) {
                ar[m][n] = __builtin_amdgcn_mfma_f32_16x16x32_bf16(xr[m], br[n], ar[m][n], 0,0,0);
                ar[m][n] = __builtin_amdgcn_mfma_f32_16x16x32_bf16(xi[m], bn[n], ar[m][n], 0,0,0);
                ai[m][n] = __builtin_amdgcn_mfma_f32_16x16x32_bf16(xr[m], bi[n], ai[m][n], 0,0,0);
                ai[m][n] = __builtin_amdgcn_mfma_f32_16x16x32_bf16(xi[m], br[n], ai[m][n], 0,0,0);
            }
    }
    #pragma unroll
    for (int m = 0; m < 4; ++m)
        #pragma unroll
        for (int n = 0; n < 2; ++n)
            #pragma unroll
            for (int j = 0; j < 4; ++j) {
                int b = wv*64 + m*16 + g2*4 + j;
                int f = wc*32 + n*16 + rl;
                Ore_g[xbase + (size_t)b*64 + f] = ar[m][n][j];
                Oim_g[xbase + (size_t)b*64 + f] = ai[m][n][j];
            }
}

// ============ fourier stage 3: iDFT (drops Im(X0)), block per (b,h), bf16 out ============
__global__ __launch_bounds__(256) void fourier3_k(
    const float* __restrict__ Ore_g, const float* __restrict__ Oim_g,
    const float* __restrict__ cosT, const float* __restrict__ sinT,
    unsigned short* __restrict__ yB)
{
    __shared__ float Ore[31][64], Oim[31][64];
    __shared__ float ct[2016], st[2016];
    int b = blockIdx.x >> 3, h = blockIdx.x & 7;
    int t = threadIdx.x;
    for (int idx = t; idx < 496; idx += 256) {
        int m = idx >> 4, e4 = idx & 15;
        size_t a = ((size_t)(h*MODES_ + m)*128 + b)*64 + e4*4;
        *(float4*)&Ore[m][e4*4] = *(const float4*)(Ore_g + a);
        *(float4*)&Oim[m][e4*4] = *(const float4*)(Oim_g + a);
    }
    for (int idx = t; idx < 504; idx += 256) {
        *(float4*)&ct[idx*4] = *(const float4*)(cosT + idx*4);
        *(float4*)&st[idx*4] = *(const float4*)(sinT + idx*4);
    }
    __syncthreads();
    int f = t & 63, w = t >> 6;
    int l0 = w*16;
    float y[16];
    float r0 = Ore[0][f];
    #pragma unroll
    for (int i = 0; i < 16; ++i) y[i] = r0;
    for (int m = 1; m < MODES_; ++m) {
        float re2 = 2.f*Ore[m][f], im2 = 2.f*Oim[m][f];
        #pragma unroll
        for (int i = 0; i < 16; ++i) {
            y[i] = fmaf(re2, ct[m*63 + l0 + i], y[i]);
            y[i] = fmaf(-im2, st[m*63 + l0 + i], y[i]);
        }
    }
    int nl = (w == 3) ? 15 : 16;
    unsigned short* yo = yB + ((size_t)(b*512) + h*64 + f) * 63 + l0;
    for (int i = 0; i < nl; ++i) yo[i] = f2b(y[i] * (1.f/63.f));
}

// ============ (X+Y) - movavg(X+Y), bf16 in/out, rolling window ============
__global__ void decomp_add_k(const unsigned short* __restrict__ X,
                             const unsigned short* __restrict__ Yv,
                             unsigned short* __restrict__ outB) {
    int idx = blockIdx.x * 256 + threadIdx.x;
    if (idx >= B_*D_) return;
    int b = idx >> 9, d = idx & 511;
    const unsigned short* xp = X  + (size_t)b * L_ * D_ + d;
    const unsigned short* yp = Yv + (size_t)b * L_ * D_ + d;
    unsigned short* ob = outB + (size_t)b * L_ * D_ + d;
    #define RD(l) (b2f(xp[(size_t)(l) * D_]) + b2f(yp[(size_t)(l) * D_]))
    float sum = 13.f * RD(0);
    #pragma unroll
    for (int j = 1; j <= 12; ++j) sum += RD(j);
    for (int l = 0; l < L_; ++l) {
        float res = RD(l) - sum * (1.f / KMA);
        ob[(size_t)l * D_] = f2b(res);
        int add = l + 13 > L_-1 ? L_-1 : l + 13;
        int rem = l - 12 < 0 ? 0 : l - 12;
        sum += RD(add) - RD(rem);
    }
    #undef RD
}

// ============ fused layernorm (row) + mean-subtract (column over L), block per b ============
__global__ __launch_bounds__(256) void ln_colmean_k(
    const unsigned short* __restrict__ Xb, const float* __restrict__ g,
    const float* __restrict__ bt, unsigned short* __restrict__ outB)
{
    __shared__ unsigned short lds[63][512];
    int b = blockIdx.x;
    int w = threadIdx.x >> 6, lane = threadIdx.x & 63;
    for (int i = 0; i < 16; ++i) {
        int row = w*16 + i;
        if (row >= 63) break;
        const unsigned short* x = Xb + ((size_t)(b*63 + row))*512 + lane*8;
        uint4 raw = *(const uint4*)x;
        const unsigned short* rp = (const unsigned short*)&raw;
        float v[8]; float s = 0.f, s2 = 0.f;
        #pragma unroll
        for (int j = 0; j < 8; ++j) { v[j] = b2f(rp[j]); s += v[j]; s2 += v[j]*v[j]; }
        #pragma unroll
        for (int o = 32; o > 0; o >>= 1) { s += __shfl_down(s, o); s2 += __shfl_down(s2, o); }
        s = __shfl(s, 0); s2 = __shfl(s2, 0);
        float mu = s * (1.f/D_);
        float var = s2 * (1.f/D_) - mu*mu;
        float rs = rsqrtf(var + 1e-5f);
        unsigned short o16[8];
        #pragma unroll
        for (int j = 0; j < 8; ++j) {
            int d = lane*8 + j;
            o16[j] = f2b((v[j] - mu) * rs * g[d] + bt[d]);
        }
        *(uint4*)&lds[row][lane*8] = *(const uint4*)o16;
    }
    __syncthreads();
    #pragma unroll
    for (int i = 0; i < 2; ++i) {
        int d = threadIdx.x + 256*i;
        float s = 0.f;
        for (int l = 0; l < 63; ++l) s += b2f(lds[l][d]);
        s *= (1.f / 63.f);
        for (int l = 0; l < 63; ++l)
            outB[((size_t)(b*63 + l))*512 + d] = f2b(b2f(lds[l][d]) - s);
    }
}

// ============ head GEMM v2: barrier-free K-loop, W direct-to-register ============
// grid (42 n-tiles of 48, 12 k-chunks of 2688). 4 waves/block each owning a 672-k slice.
// W: global f32 -> regs -> bf16 (private per wave). A: global bf16 -> regs (L3-hot).
// Wave partials reduced via LDS at end; 12 k-chunk parts summed by reduce_k.
__global__ __launch_bounds__(256) void head_mfma(
    const unsigned short* __restrict__ A,
    const float* __restrict__ W,
    float* __restrict__ parts)
{
    __shared__ float red[128][48];
    int nt = blockIdx.x;       // 0..41
    int kc = blockIdx.y;       // 0..11
    int wv = threadIdx.x >> 6, lane = threadIdx.x & 63;
    int rl = lane & 15, g2 = lane >> 4;
    f32x4 acc[8][3] = {};
    const unsigned short* Ab = A + (size_t)rl * KHEAD;
    const float* Wb = W + (size_t)(nt*48 + rl) * KHEAD;
    int kbeg = kc*2688 + wv*672 + g2*8;

    for (int ks = 0; ks < 21; ++ks) {
        int k = kbeg + ks*32;
        short8 af[8];
        #pragma unroll
        for (int m = 0; m < 8; ++m)
            af[m] = *(const short8*)(Ab + (size_t)(m*16) * KHEAD + k);
        short8 wf[3];
        #pragma unroll
        for (int n = 0; n < 3; ++n) {
            float4 lo = *(const float4*)(Wb + (size_t)(n*16) * KHEAD + k);
            float4 hi = *(const float4*)(Wb + (size_t)(n*16) * KHEAD + k + 4);
            unsigned short u[8] = { f2b(lo.x), f2b(lo.y), f2b(lo.z), f2b(lo.w),
                                    f2b(hi.x), f2b(hi.y), f2b(hi.z), f2b(hi.w) };
            wf[n] = *(const short8*)u;
        }
        #pragma unroll
        for (int m = 0; m < 8; ++m)
            #pragma unroll
            for (int n = 0; n < 3; ++n)
                acc[m][n] = __builtin_amdgcn_mfma_f32_16x16x32_bf16(af[m], wf[n], acc[m][n], 0,0,0);
    }

    // reduce 4 wave-partials via LDS (turn-based)
    for (int w = 0; w < 4; ++w) {
        if (wv == w) {
            #pragma unroll
            for (int m = 0; m < 8; ++m)
                #pragma unroll
                for (int n = 0; n < 3; ++n)
                    #pragma unroll
                    for (int j = 0; j < 4; ++j) {
                        int row = m*16 + g2*4 + j, col = n*16 + rl;
                        if (w == 0) red[row][col] = acc[m][n][j];
                        else        red[row][col] += acc[m][n][j];
                    }
        }
        __syncthreads();
    }
    float* pout = parts + (size_t)kc * (B_*NOUT);
    for (int idx = threadIdx.x; idx < 128*48; idx += 256) {
        int row = idx / 48, col = idx % 48;
        pout[(size_t)row * NOUT + nt*48 + col] = red[row][col];
    }
}

// ============ out = trendout + sum of 12 parts ============
__global__ void reduce_k(const float* __restrict__ trendout, const float* __restrict__ parts,
                         float* __restrict__ out) {
    int i = blockIdx.x * 256 + threadIdx.x;
    if (i >= 64512) return;
    float4 s = ((const float4*)trendout)[i];
    for (int kc = 0; kc < 12; ++kc) {
        float4 p = ((const float4*)parts)[(size_t)kc * 64512 + i];
        s.x += p.x; s.y += p.y; s.z += p.z; s.w += p.w;
    }
    ((float4*)out)[i] = s;
}

extern "C" void kernel_launch(void* const* d_in, const int* in_sizes, int n_in,
                              void* d_out, int out_size, void* d_ws, size_t ws_size,
                              hipStream_t stream) {
    const float* x_enc   = (const float*)d_in[0];
    const float* patch_W = (const float*)d_in[4];
    const float* patch_b = (const float*)d_in[5];
    const float* Wq      = (const float*)d_in[6];
    const float* bq      = (const float*)d_in[7];
    const float* Wo      = (const float*)d_in[8];
    const float* bo      = (const float*)d_in[9];
    const float* four_wr = (const float*)d_in[10];
    const float* four_wi = (const float*)d_in[11];
    const float* c1      = (const float*)d_in[12];
    const float* c2      = (const float*)d_in[13];
    const float* gamma   = (const float*)d_in[14];
    const float* beta    = (const float*)d_in[15];
    const float* head_W  = (const float*)d_in[16];
    const float* head_b  = (const float*)d_in[17];
    const float* trend_W = (const float*)d_in[18];
    const float* trend_b = (const float*)d_in[19];
    float* out = (float*)d_out;
    float* ws  = (float*)d_ws;

    unsigned short* seasB  = (unsigned short*)ws;
    unsigned short* trendB = (unsigned short*)(ws + 688128);
    unsigned short* xpB    = (unsigned short*)(ws + 1376256);
    unsigned short* bufAb  = (unsigned short*)(ws + 2924544);
    unsigned short* tmpB16 = (unsigned short*)(ws + 4988928);
    unsigned short* tmp2   = (unsigned short*)(ws + 7053312);
    unsigned short* bufCb  = (unsigned short*)(ws + 9117696);
    float* qF    = ws + 11182080;
    float* Ore_g = qF;
    float* Oim_g = qF + 2031616;
    float* big   = ws + 15310848;
    unsigned short* hidB = (unsigned short*)big;
    float* Xre_g = big;
    float* Xim_g = big + 2031616;
    unsigned short* WqB = (unsigned short*)(ws + 23568384);
    unsigned short* WoB = (unsigned short*)(ws + 23830528);
    unsigned short* c1B = (unsigned short*)(ws + 24092672);
    unsigned short* c2B = (unsigned short*)(ws + 25141248);
    unsigned short* pWB = (unsigned short*)(ws + 26189824);
    float* cosT = ws + 26288128;
    float* sinT = ws + 26290144;
    float* trendout = ws + 26292160;
    float* parts = ws + 26550208;     // 12 * 258048 floats

    auto cdiv = [](int a, int b) { return (a + b - 1) / b; };

    prep_k<<<5321,256,0,stream>>>(Wq, Wo, c1, c2, WqB, WoB, c1B, c2B, patch_W, pWB, cosT, sinT);
    decomp_input_k<<<cdiv(B_*C_*16,256),256,0,stream>>>(x_enc, seasB, trendB);
    patches_k<<<cdiv(B_*L_*384,256),256,0,stream>>>(seasB, xpB);
    trend_mfma<<<42,256,0,stream>>>(trendB, trend_W, trend_b, head_b, trendout);

    gemm_mfma<<<dim3(4,126),256,0,stream>>>(xpB, pWB, patch_b, (float*)nullptr, bufAb, ML, 512, 384, 0);

    for (int l = 0; l < 2; ++l) {
        const unsigned short* WqB_l = WqB + (size_t)l*512*512;
        const unsigned short* WoB_l = WoB + (size_t)l*512*512;
        const unsigned short* c1B_l = c1B + (size_t)l*FF_*D_;
        const unsigned short* c2B_l = c2B + (size_t)l*D_*FF_;
        const float* bq_l = bq + (size_t)l*512;
        const float* bo_l = bo + (size_t)l*512;
        const float* wr_l = four_wr + (size_t)l*H_*DH_*DH_*MODES_;
        const float* wi_l = four_wi + (size_t)l*H_*DH_*DH_*MODES_;

        gemm_mfma<<<dim3(4,126),256,0,stream>>>(bufAb, WqB_l, bq_l, qF, (unsigned short*)nullptr, ML, 512, 512, 0);
        fourier1_k<<<B_*H_,256,0,stream>>>(qF, cosT, sinT, Xre_g, Xim_g);
        fourier2_k<<<H_*MODES_,256,0,stream>>>(Xre_g, Xim_g, wr_l, wi_l, Ore_g, Oim_g);
        fourier3_k<<<B_*H_,256,0,stream>>>(Ore_g, Oim_g, cosT, sinT, tmpB16);
        gemm_mfma<<<dim3(4,126),256,0,stream>>>(tmpB16, WoB_l, bo_l, (float*)nullptr, tmp2, ML, 512, 512, 0);
        decomp_add_k<<<cdiv(B_*D_,256),256,0,stream>>>(bufAb, tmp2, bufCb);
        gemm_mfma<<<dim3(16,126),256,0,stream>>>(bufCb, c1B_l, (const float*)nullptr, (float*)nullptr, hidB, ML, FF_, 512, 1);
        gemm_mfma<<<dim3(4,126),256,0,stream>>>(hidB, c2B_l, (const float*)nullptr, (float*)nullptr, tmp2, ML, 512, FF_, 0);
        decomp_add_k<<<cdiv(B_*D_,256),256,0,stream>>>(bufCb, tmp2, bufAb);
    }

    ln_colmean_k<<<B_,256,0,stream>>>(bufAb, gamma, beta, tmpB16);
    head_mfma<<<dim3(42,12),256,0,stream>>>(tmpB16, head_W, parts);
    reduce_k<<<cdiv(64512,256),256,0,stream>>>(trendout, parts, out);
}

// Round 9
// 555.350 us; speedup vs baseline: 1.0017x; 1.0014x over previous
//
#include <hip/hip_runtime.h>
#include <math.h>

#define B_ 128
#define T_ 512
#define C_ 21
#define L_ 63
#define D_ 512
#define H_ 8
#define DH_ 64
#define MODES_ 31
#define FF_ 2048
#define P_ 96
#define KMA 25
#define PAD 12
#define NOUT (P_*C_)      /* 2016 */
#define KHEAD (L_*D_)     /* 32256 */
#define ML (B_*L_)        /* 8064 rows */

typedef __attribute__((ext_vector_type(8))) short short8;
typedef __attribute__((ext_vector_type(4))) float f32x4;

__device__ __forceinline__ unsigned short f2b(float f) {
    union { float f; unsigned u; } v; v.f = f;
    unsigned r = v.u + 0x7FFFu + ((v.u >> 16) & 1u);
    return (unsigned short)(r >> 16);
}
__device__ __forceinline__ float b2f(unsigned short u) {
    union { unsigned u; float f; } v; v.u = ((unsigned)u) << 16;
    return v.f;
}
__device__ __forceinline__ void gld_lds16(const void* g, void* l) {
    __builtin_amdgcn_global_load_lds(
        (const __attribute__((address_space(1))) unsigned int*)g,
        (__attribute__((address_space(3))) unsigned int*)l, 16, 0, 0);
}

// ============ prep: all weight conversions + pad + DFT tables, one kernel ============
__global__ void prep_k(const float* __restrict__ Wq, const float* __restrict__ Wo,
                       const float* __restrict__ c1, const float* __restrict__ c2,
                       unsigned short* __restrict__ WqB, unsigned short* __restrict__ WoB,
                       unsigned short* __restrict__ c1B, unsigned short* __restrict__ c2B,
                       const float* __restrict__ pW, unsigned short* __restrict__ pWB,
                       float* __restrict__ cosT, float* __restrict__ sinT) {
    int i = blockIdx.x * 256 + threadIdx.x;
    if (i < 262144) {
        const float* src = (i < 131072) ? Wq : Wo;
        unsigned short* dst = (i < 131072) ? WqB : WoB;
        int j = i & 131071;
        float4 v = ((const float4*)src)[j];
        uint2 p; p.x = (unsigned)f2b(v.x) | ((unsigned)f2b(v.y) << 16);
        p.y = (unsigned)f2b(v.z) | ((unsigned)f2b(v.w) << 16);
        ((uint2*)dst)[j] = p;
    } else if (i < 1310720) {
        int j = i - 262144;
        const float* src = (j < 524288) ? c1 : c2;
        unsigned short* dst = (j < 524288) ? c1B : c2B;
        j &= 524287;
        float4 v = ((const float4*)src)[j];
        uint2 p; p.x = (unsigned)f2b(v.x) | ((unsigned)f2b(v.y) << 16);
        p.y = (unsigned)f2b(v.z) | ((unsigned)f2b(v.w) << 16);
        ((uint2*)dst)[j] = p;
    } else if (i < 1359872) {
        int j = i - 1310720;
        int row = j / 96, c4 = j % 96;
        uint2 p; p.x = 0; p.y = 0;
        if (c4 < 84) {
            float4 v = *(const float4*)(pW + (size_t)row * 336 + c4 * 4);
            p.x = (unsigned)f2b(v.x) | ((unsigned)f2b(v.y) << 16);
            p.y = (unsigned)f2b(v.z) | ((unsigned)f2b(v.w) << 16);
        }
        ((uint2*)pWB)[j] = p;
    } else if (i < 1361888) {
        int j = i - 1359872;
        int m = j / 63, l = j % 63;
        if (m >= MODES_) { cosT[j] = 0.f; sinT[j] = 0.f; }
        else {
            int r = (m * l) % 63;
            double a = 6.283185307179586476925286766559 * (double)r / 63.0;
            cosT[j] = (float)cos(a); sinT[j] = (float)sin(a);
        }
    }
}

// ============ series_decomp on input, rolling window, bf16 outputs ============
__global__ void decomp_input_k(const float* __restrict__ x,
                               unsigned short* __restrict__ seasB,
                               unsigned short* __restrict__ trendB) {
    int idx = blockIdx.x * 256 + threadIdx.x;
    if (idx >= B_ * C_ * 16) return;
    int tc = idx & 15; int rc = idx >> 4; int c = rc % C_; int b = rc / C_;
    const float* xb = x + (size_t)b * T_ * C_ + c;
    int t0 = tc * 32;
    float sum = 0.f;
    #pragma unroll
    for (int i = -PAD; i <= PAD; ++i) {
        int tt = t0 + i; tt = tt < 0 ? 0 : (tt > T_-1 ? T_-1 : tt);
        sum += xb[(size_t)tt * C_];
    }
    for (int t = t0; t < t0 + 32; ++t) {
        float mean = sum * (1.f / KMA);
        float xv = xb[(size_t)t * C_];
        size_t o = ((size_t)b * T_ + t) * C_ + c;
        seasB[o]  = f2b(xv - mean);
        trendB[o] = f2b(mean);
        int add = t + 13 > T_-1 ? T_-1 : t + 13;
        int rem = t - 12 < 0 ? 0 : t - 12;
        sum += xb[(size_t)add * C_] - xb[(size_t)rem * C_];
    }
}

// ============ gather patches (bf16 -> bf16, zero-padded K 336->384) ============
__global__ void patches_k(const unsigned short* __restrict__ seasB,
                          unsigned short* __restrict__ xpB) {
    int idx = blockIdx.x * 256 + threadIdx.x;
    if (idx >= B_*L_*384) return;
    int col = idx % 384; int r = idx / 384; int n = r % L_; int b = r / L_;
    unsigned short v = 0;
    if (col < 336) {
        int c = col >> 4; int j = col & 15;
        v = seasB[((size_t)b * T_ + 8*n + j) * C_ + c];
    }
    xpB[idx] = v;
}

// ============ trend head as MFMA GEMM: M=2688 (b,c), N=96 (p), K=512 (t) ============
__global__ __launch_bounds__(256) void trend_mfma(
    const unsigned short* __restrict__ trendB, const float* __restrict__ tW,
    const float* __restrict__ tb, const float* __restrict__ hb,
    float* __restrict__ outT)
{
    __shared__ unsigned short Asl[64*32];
    __shared__ unsigned short Wsl[96*32];
    int bm = blockIdx.x;
    int t = threadIdx.x, wave = t >> 6, lane = t & 63;
    int wr = wave >> 1, wc = wave & 1, g2 = lane >> 4, rl = lane & 15;
    f32x4 acc[2][3] = {};
    int ar = t >> 2, aslot = t & 3;
    int rowg = bm*64 + ar; int ab = rowg / 21, ac = rowg % 21;
    for (int k0 = 0; k0 < 512; k0 += 32) {
        __syncthreads();
        {
            unsigned short vals[8];
            int kb = k0 + aslot*8;
            #pragma unroll
            for (int j = 0; j < 8; ++j)
                vals[j] = trendB[((size_t)ab * T_ + kb + j) * C_ + ac];
            int phys = aslot ^ ((ar>>1)&3);
            *(uint4*)&Asl[ar*32 + phys*8] = *(const uint4*)vals;
        }
        #pragma unroll
        for (int i = 0; i < 3; ++i) {
            int idx = t + 256*i;
            int r = idx >> 3, c4 = idx & 7;
            float4 w4 = *(const float4*)(tW + (size_t)r * T_ + k0 + c4*4);
            uint2 p; p.x = (unsigned)f2b(w4.x) | ((unsigned)f2b(w4.y) << 16);
            p.y = (unsigned)f2b(w4.z) | ((unsigned)f2b(w4.w) << 16);
            *(uint2*)&Wsl[r*32 + (((c4>>1) ^ ((r>>1)&3)) << 3) + ((c4&1) << 2)] = p;
        }
        __syncthreads();
        short8 af[2], wf[3];
        #pragma unroll
        for (int m = 0; m < 2; ++m) {
            int r = wr*32 + m*16 + rl;
            af[m] = *(const short8*)&Asl[r*32 + ((g2 ^ ((r>>1)&3)) << 3)];
        }
        #pragma unroll
        for (int n = 0; n < 3; ++n) {
            int r = wc*48 + n*16 + rl;
            wf[n] = *(const short8*)&Wsl[r*32 + ((g2 ^ ((r>>1)&3)) << 3)];
        }
        #pragma unroll
        for (int m = 0; m < 2; ++m)
            #pragma unroll
            for (int n = 0; n < 3; ++n)
                acc[m][n] = __builtin_amdgcn_mfma_f32_16x16x32_bf16(af[m], wf[n], acc[m][n], 0,0,0);
    }
    #pragma unroll
    for (int n = 0; n < 3; ++n) {
        int p = wc*48 + n*16 + rl;
        float bias = tb[p];
        #pragma unroll
        for (int m = 0; m < 2; ++m)
            #pragma unroll
            for (int j = 0; j < 4; ++j) {
                int rg = bm*64 + wr*32 + m*16 + g2*4 + j;
                int b = rg / 21, c = rg % 21;
                outT[(size_t)b * NOUT + p*21 + c] = acc[m][n][j] + bias + hb[p*21 + c];
            }
    }
}

// ============ bf16 MFMA GEMM, tile 64(M)x128(N), BK=64, double-buffered (1 barrier/step) ============
__global__ __launch_bounds__(256) void gemm_mfma(
    const unsigned short* __restrict__ A,
    const unsigned short* __restrict__ W,
    const float* __restrict__ bias,
    float* __restrict__ Cf,
    unsigned short* __restrict__ Cb,
    int M, int N, int K, int act)
{
    __shared__ unsigned short Asl[2][64*64];
    __shared__ unsigned short Wsl[2][128*64];
    int bm = blockIdx.y, bn = blockIdx.x;
    int t = threadIdx.x;
    int wave = t >> 6, lane = t & 63;
    int wr = wave >> 1, wc = wave & 1;
    int g2 = lane >> 4, rl = lane & 15;
    int lr8 = lane >> 3, l7 = lane & 7;
    f32x4 acc[2][4] = {};
    const unsigned short* Ab = A + (size_t)(bm*64) * K;
    const unsigned short* Wb = W + (size_t)(bn*128) * K;

    // prologue: stage k0=0 into buffer 0
    #pragma unroll
    for (int i = 0; i < 2; ++i) {
        int seg = wave*2 + i;
        int r = seg*8 + lr8;
        int ko = (l7 ^ (r & 7)) << 3;
        gld_lds16(Ab + (size_t)r*K + ko, &Asl[0][seg*512]);
    }
    #pragma unroll
    for (int i = 0; i < 4; ++i) {
        int seg = wave*4 + i;
        int r = seg*8 + lr8;
        int ko = (l7 ^ (r & 7)) << 3;
        gld_lds16(Wb + (size_t)r*K + ko, &Wsl[0][seg*512]);
    }

    int cur = 0;
    for (int k0 = 0; k0 < K; k0 += 64, cur ^= 1) {
        __syncthreads();   // drains this wave's outstanding stage + prior reads
        if (k0 + 64 < K) {
            int kn = k0 + 64;
            #pragma unroll
            for (int i = 0; i < 2; ++i) {
                int seg = wave*2 + i;
                int r = seg*8 + lr8;
                int ko = (l7 ^ (r & 7)) << 3;
                gld_lds16(Ab + (size_t)r*K + kn + ko, &Asl[cur^1][seg*512]);
            }
            #pragma unroll
            for (int i = 0; i < 4; ++i) {
                int seg = wave*4 + i;
                int r = seg*8 + lr8;
                int ko = (l7 ^ (r & 7)) << 3;
                gld_lds16(Wb + (size_t)r*K + kn + ko, &Wsl[cur^1][seg*512]);
            }
        }
        short8 af[2][2], wf[2][4];
        #pragma unroll
        for (int sub = 0; sub < 2; ++sub) {
            #pragma unroll
            for (int m = 0; m < 2; ++m) {
                int r = wr*32 + m*16 + rl;
                af[sub][m] = *(const short8*)&Asl[cur][r*64 + (((sub*4+g2) ^ (r&7)) << 3)];
            }
            #pragma unroll
            for (int n = 0; n < 4; ++n) {
                int r = wc*64 + n*16 + rl;
                wf[sub][n] = *(const short8*)&Wsl[cur][r*64 + (((sub*4+g2) ^ (r&7)) << 3)];
            }
        }
        #pragma unroll
        for (int sub = 0; sub < 2; ++sub)
            #pragma unroll
            for (int m = 0; m < 2; ++m)
                #pragma unroll
                for (int n = 0; n < 4; ++n)
                    acc[m][n] = __builtin_amdgcn_mfma_f32_16x16x32_bf16(af[sub][m], wf[sub][n], acc[m][n], 0,0,0);
    }

    int crow0 = bm*64 + wr*32;
    int ccol0 = bn*128 + wc*64;
    #pragma unroll
    for (int n = 0; n < 4; ++n) {
        int col = ccol0 + n*16 + rl;
        float bv = bias ? bias[col] : 0.f;
        #pragma unroll
        for (int m = 0; m < 2; ++m) {
            #pragma unroll
            for (int j = 0; j < 4; ++j) {
                int row = crow0 + m*16 + g2*4 + j;
                float x = acc[m][n][j] + bv;
                if (act == 1) x = 0.5f * x * (1.f + erff(x * 0.70710678118654752f));
                size_t ix = (size_t)row * N + col;
                if (Cf) Cf[ix] = x;
                if (Cb) Cb[ix] = f2b(x);
            }
        }
    }
}

// ============ fourier stage 1: DFT, block per (b,h) ============
__global__ __launch_bounds__(256) void fourier1_k(
    const float* __restrict__ q, const float* __restrict__ cosT, const float* __restrict__ sinT,
    float* __restrict__ Xre_g, float* __restrict__ Xim_g)
{
    __shared__ float qs[63][64];
    __shared__ float ct[2016], st[2016];
    int b = blockIdx.x >> 3, h = blockIdx.x & 7;
    int t = threadIdx.x;
    for (int idx = t; idx < 1008; idx += 256) {
        int l = idx >> 4, e4 = idx & 15;
        *(float4*)&qs[l][e4*4] = *(const float4*)(q + ((size_t)(b*63 + l))*512 + h*64 + e4*4);
    }
    for (int idx = t; idx < 504; idx += 256) {
        *(float4*)&ct[idx*4] = *(const float4*)(cosT + idx*4);
        *(float4*)&st[idx*4] = *(const float4*)(sinT + idx*4);
    }
    __syncthreads();
    int mm = t & 31, g = t >> 5;
    float re[8] = {}, im[8] = {};
    for (int l = 0; l < 63; ++l) {
        float c = ct[mm*63 + l], s = st[mm*63 + l];
        #pragma unroll
        for (int j = 0; j < 8; ++j) {
            float v = qs[l][g*8 + j];
            re[j] = fmaf(v, c, re[j]);
            im[j] = fmaf(-v, s, im[j]);
        }
    }
    if (mm < MODES_) {
        size_t base = ((size_t)(h*MODES_ + mm)*128 + b)*64 + g*8;
        *(float4*)&Xre_g[base]   = *(float4*)&re[0];
        *(float4*)&Xre_g[base+4] = *(float4*)&re[4];
        *(float4*)&Xim_g[base]   = *(float4*)&im[0];
        *(float4*)&Xim_g[base+4] = *(float4*)&im[4];
    }
}

// ============ fourier stage 2: complex mode-mix via bf16 MFMA, block per (h,m) ============
__global__ __launch_bounds__(256) void fourier2_k(
    const float* __restrict__ Xre_g, const float* __restrict__ Xim_g,
    const float* __restrict__ wr, const float* __restrict__ wi,
    float* __restrict__ Ore_g, float* __restrict__ Oim_g)
{
    __shared__ unsigned short Xr[128*64], Xi[128*64];
    __shared__ unsigned short Wr[64*64], Wi[64*64], Wn[64*64];
    int h = blockIdx.x / MODES_, mm = blockIdx.x % MODES_;
    int t = threadIdx.x;
    size_t xbase = ((size_t)(h*MODES_ + mm)) * 128 * 64;
    #pragma unroll
    for (int i = 0; i < 8; ++i) {
        int idx = t + 256*i;
        int r = idx >> 4, c4 = idx & 15;
        int ad = r*64 + (((c4>>1) ^ (r&7)) << 3) + ((c4&1) << 2);
        float4 v = *(const float4*)(Xre_g + xbase + (size_t)r*64 + c4*4);
        uint2 p; p.x = (unsigned)f2b(v.x) | ((unsigned)f2b(v.y) << 16);
        p.y = (unsigned)f2b(v.z) | ((unsigned)f2b(v.w) << 16);
        *(uint2*)&Xr[ad] = p;
        v = *(const float4*)(Xim_g + xbase + (size_t)r*64 + c4*4);
        p.x = (unsigned)f2b(v.x) | ((unsigned)f2b(v.y) << 16);
        p.y = (unsigned)f2b(v.z) | ((unsigned)f2b(v.w) << 16);
        *(uint2*)&Xi[ad] = p;
    }
    #pragma unroll
    for (int i = 0; i < 2; ++i) {
        int idx = t + 256*i;
        int f = idx >> 3, oct = idx & 7;
        unsigned short wrv[8], wiv[8], wnv[8];
        #pragma unroll
        for (int j = 0; j < 8; ++j) {
            int e = oct*8 + j;
            size_t a = (((size_t)(h*64 + e))*64 + f)*MODES_ + mm;
            wrv[j] = f2b(wr[a]);
            wiv[j] = f2b(wi[a]);
            wnv[j] = wiv[j] ^ 0x8000u;
        }
        int ad = f*64 + ((oct ^ (f&7)) << 3);
        *(uint4*)&Wr[ad] = *(const uint4*)wrv;
        *(uint4*)&Wi[ad] = *(const uint4*)wiv;
        *(uint4*)&Wn[ad] = *(const uint4*)wnv;
    }
    __syncthreads();
    int wave = t >> 6, lane = t & 63;
    int wv = wave >> 1, wc = wave & 1;
    int g2 = lane >> 4, rl = lane & 15;
    f32x4 ar[4][2] = {}, ai[4][2] = {};
    #pragma unroll
    for (int sub = 0; sub < 2; ++sub) {
        short8 xr[4], xi[4], br[2], bi[2], bn[2];
        #pragma unroll
        for (int m = 0; m < 4; ++m) {
            int r = wv*64 + m*16 + rl;
            int off = r*64 + (((sub*4+g2) ^ (r&7)) << 3);
            xr[m] = *(const short8*)&Xr[off];
            xi[m] = *(const short8*)&Xi[off];
        }
        #pragma unroll
        for (int n = 0; n < 2; ++n) {
            int r = wc*32 + n*16 + rl;
            int off = r*64 + (((sub*4+g2) ^ (r&7)) << 3);
            br[n] = *(const short8*)&Wr[off];
            bi[n] = *(const short8*)&Wi[off];
            bn[n] = *(const short8*)&Wn[off];
        }
        #pragma unroll
        for (int m = 0; m < 4; ++m)
            #pragma unroll
            for (int n = 0; n < 2; ++n) {
                ar[m][n] = __builtin_amdgcn_mfma_f32_16x16x32_bf16(xr[m], br[n], ar[m][n], 0,0,0);
                ar[m][n] = __builtin_amdgcn_mfma_f32_16x16x32_bf16(xi[m], bn[n], ar[m][n], 0,0,0);
                ai[m][n] = __builtin_amdgcn_mfma_f32_16x16x32_bf16(xr[m], bi[n], ai[m][n], 0,0,0);
                ai[m][n] = __builtin_amdgcn_mfma_f32_16x16x32_bf16(xi[m], br[n], ai[m][n], 0,0,0);
            }
    }
    #pragma unroll
    for (int m = 0; m < 4; ++m)
        #pragma unroll
        for (int n = 0; n < 2; ++n)
            #pragma unroll
            for (int j = 0; j < 4; ++j) {
                int b = wv*64 + m*16 + g2*4 + j;
                int f = wc*32 + n*16 + rl;
                Ore_g[xbase + (size_t)b*64 + f] = ar[m][n][j];
                Oim_g[xbase + (size_t)b*64 + f] = ai[m][n][j];
            }
}

// ============ fourier stage 3: iDFT (drops Im(X0)), block per (b,h), bf16 out ============
__global__ __launch_bounds__(256) void fourier3_k(
    const float* __restrict__ Ore_g, const float* __restrict__ Oim_g,
    const float* __restrict__ cosT, const float* __restrict__ sinT,
    unsigned short* __restrict__ yB)
{
    __shared__ float Ore[31][64], Oim[31][64];
    __shared__ float ct[2016], st[2016];
    int b = blockIdx.x >> 3, h = blockIdx.x & 7;
    int t = threadIdx.x;
    for (int idx = t; idx < 496; idx += 256) {
        int m = idx >> 4, e4 = idx & 15;
        size_t a = ((size_t)(h*MODES_ + m)*128 + b)*64 + e4*4;
        *(float4*)&Ore[m][e4*4] = *(const float4*)(Ore_g + a);
        *(float4*)&Oim[m][e4*4] = *(const float4*)(Oim_g + a);
    }
    for (int idx = t; idx < 504; idx += 256) {
        *(float4*)&ct[idx*4] = *(const float4*)(cosT + idx*4);
        *(float4*)&st[idx*4] = *(const float4*)(sinT + idx*4);
    }
    __syncthreads();
    int f = t & 63, w = t >> 6;
    int l0 = w*16;
    float y[16];
    float r0 = Ore[0][f];
    #pragma unroll
    for (int i = 0; i < 16; ++i) y[i] = r0;
    for (int m = 1; m < MODES_; ++m) {
        float re2 = 2.f*Ore[m][f], im2 = 2.f*Oim[m][f];
        #pragma unroll
        for (int i = 0; i < 16; ++i) {
            y[i] = fmaf(re2, ct[m*63 + l0 + i], y[i]);
            y[i] = fmaf(-im2, st[m*63 + l0 + i], y[i]);
        }
    }
    int nl = (w == 3) ? 15 : 16;
    unsigned short* yo = yB + ((size_t)(b*512) + h*64 + f) * 63 + l0;
    for (int i = 0; i < nl; ++i) yo[i] = f2b(y[i] * (1.f/63.f));
}

// ============ (X+Y) - movavg(X+Y), bf16 in/out, rolling window ============
__global__ void decomp_add_k(const unsigned short* __restrict__ X,
                             const unsigned short* __restrict__ Yv,
                             unsigned short* __restrict__ outB) {
    int idx = blockIdx.x * 256 + threadIdx.x;
    if (idx >= B_*D_) return;
    int b = idx >> 9, d = idx & 511;
    const unsigned short* xp = X  + (size_t)b * L_ * D_ + d;
    const unsigned short* yp = Yv + (size_t)b * L_ * D_ + d;
    unsigned short* ob = outB + (size_t)b * L_ * D_ + d;
    #define RD(l) (b2f(xp[(size_t)(l) * D_]) + b2f(yp[(size_t)(l) * D_]))
    float sum = 13.f * RD(0);
    #pragma unroll
    for (int j = 1; j <= 12; ++j) sum += RD(j);
    for (int l = 0; l < L_; ++l) {
        float res = RD(l) - sum * (1.f / KMA);
        ob[(size_t)l * D_] = f2b(res);
        int add = l + 13 > L_-1 ? L_-1 : l + 13;
        int rem = l - 12 < 0 ? 0 : l - 12;
        sum += RD(add) - RD(rem);
    }
    #undef RD
}

// ============ fused layernorm (row) + mean-subtract (column over L), block per b ============
__global__ __launch_bounds__(256) void ln_colmean_k(
    const unsigned short* __restrict__ Xb, const float* __restrict__ g,
    const float* __restrict__ bt, unsigned short* __restrict__ outB)
{
    __shared__ unsigned short lds[63][512];
    int b = blockIdx.x;
    int w = threadIdx.x >> 6, lane = threadIdx.x & 63;
    for (int i = 0; i < 16; ++i) {
        int row = w*16 + i;
        if (row >= 63) break;
        const unsigned short* x = Xb + ((size_t)(b*63 + row))*512 + lane*8;
        uint4 raw = *(const uint4*)x;
        const unsigned short* rp = (const unsigned short*)&raw;
        float v[8]; float s = 0.f, s2 = 0.f;
        #pragma unroll
        for (int j = 0; j < 8; ++j) { v[j] = b2f(rp[j]); s += v[j]; s2 += v[j]*v[j]; }
        #pragma unroll
        for (int o = 32; o > 0; o >>= 1) { s += __shfl_down(s, o); s2 += __shfl_down(s2, o); }
        s = __shfl(s, 0); s2 = __shfl(s2, 0);
        float mu = s * (1.f/D_);
        float var = s2 * (1.f/D_) - mu*mu;
        float rs = rsqrtf(var + 1e-5f);
        unsigned short o16[8];
        #pragma unroll
        for (int j = 0; j < 8; ++j) {
            int d = lane*8 + j;
            o16[j] = f2b((v[j] - mu) * rs * g[d] + bt[d]);
        }
        *(uint4*)&lds[row][lane*8] = *(const uint4*)o16;
    }
    __syncthreads();
    #pragma unroll
    for (int i = 0; i < 2; ++i) {
        int d = threadIdx.x + 256*i;
        float s = 0.f;
        for (int l = 0; l < 63; ++l) s += b2f(lds[l][d]);
        s *= (1.f / 63.f);
        for (int l = 0; l < 63; ++l)
            outB[((size_t)(b*63 + l))*512 + d] = f2b(b2f(lds[l][d]) - s);
    }
}

// ============ head GEMM v2: barrier-free K-loop, W direct-to-register ============
// grid (42 n-tiles of 48, 12 k-chunks of 2688). 4 waves/block each owning a 672-k slice.
// W: global f32 -> regs -> bf16 (private per wave). A: global bf16 -> regs (L3-hot).
// Wave partials reduced via LDS at end; 12 k-chunk parts summed by reduce_k.
__global__ __launch_bounds__(256) void head_mfma(
    const unsigned short* __restrict__ A,
    const float* __restrict__ W,
    float* __restrict__ parts)
{
    __shared__ float red[128][48];
    int nt = blockIdx.x;       // 0..41
    int kc = blockIdx.y;       // 0..11
    int wv = threadIdx.x >> 6, lane = threadIdx.x & 63;
    int rl = lane & 15, g2 = lane >> 4;
    f32x4 acc[8][3] = {};
    const unsigned short* Ab = A + (size_t)rl * KHEAD;
    const float* Wb = W + (size_t)(nt*48 + rl) * KHEAD;
    int kbeg = kc*2688 + wv*672 + g2*8;

    for (int ks = 0; ks < 21; ++ks) {
        int k = kbeg + ks*32;
        short8 af[8];
        #pragma unroll
        for (int m = 0; m < 8; ++m)
            af[m] = *(const short8*)(Ab + (size_t)(m*16) * KHEAD + k);
        short8 wf[3];
        #pragma unroll
        for (int n = 0; n < 3; ++n) {
            float4 lo = *(const float4*)(Wb + (size_t)(n*16) * KHEAD + k);
            float4 hi = *(const float4*)(Wb + (size_t)(n*16) * KHEAD + k + 4);
            unsigned short u[8] = { f2b(lo.x), f2b(lo.y), f2b(lo.z), f2b(lo.w),
                                    f2b(hi.x), f2b(hi.y), f2b(hi.z), f2b(hi.w) };
            wf[n] = *(const short8*)u;
        }
        #pragma unroll
        for (int m = 0; m < 8; ++m)
            #pragma unroll
            for (int n = 0; n < 3; ++n)
                acc[m][n] = __builtin_amdgcn_mfma_f32_16x16x32_bf16(af[m], wf[n], acc[m][n], 0,0,0);
    }

    // reduce 4 wave-partials via LDS (turn-based)
    for (int w = 0; w < 4; ++w) {
        if (wv == w) {
            #pragma unroll
            for (int m = 0; m < 8; ++m)
                #pragma unroll
                for (int n = 0; n < 3; ++n)
                    #pragma unroll
                    for (int j = 0; j < 4; ++j) {
                        int row = m*16 + g2*4 + j, col = n*16 + rl;
                        if (w == 0) red[row][col] = acc[m][n][j];
                        else        red[row][col] += acc[m][n][j];
                    }
        }
        __syncthreads();
    }
    float* pout = parts + (size_t)kc * (B_*NOUT);
    for (int idx = threadIdx.x; idx < 128*48; idx += 256) {
        int row = idx / 48, col = idx % 48;
        pout[(size_t)row * NOUT + nt*48 + col] = red[row][col];
    }
}

// ============ out = trendout + sum of 12 parts ============
__global__ void reduce_k(const float* __restrict__ trendout, const float* __restrict__ parts,
                         float* __restrict__ out) {
    int i = blockIdx.x * 256 + threadIdx.x;
    if (i >= 64512) return;
    float4 s = ((const float4*)trendout)[i];
    for (int kc = 0; kc < 12; ++kc) {
        float4 p = ((const float4*)parts)[(size_t)kc * 64512 + i];
        s.x += p.x; s.y += p.y; s.z += p.z; s.w += p.w;
    }
    ((float4*)out)[i] = s;
}

extern "C" void kernel_launch(void* const* d_in, const int* in_sizes, int n_in,
                              void* d_out, int out_size, void* d_ws, size_t ws_size,
                              hipStream_t stream) {
    const float* x_enc   = (const float*)d_in[0];
    const float* patch_W = (const float*)d_in[4];
    const float* patch_b = (const float*)d_in[5];
    const float* Wq      = (const float*)d_in[6];
    const float* bq      = (const float*)d_in[7];
    const float* Wo      = (const float*)d_in[8];
    const float* bo      = (const float*)d_in[9];
    const float* four_wr = (const float*)d_in[10];
    const float* four_wi = (const float*)d_in[11];
    const float* c1      = (const float*)d_in[12];
    const float* c2      = (const float*)d_in[13];
    const float* gamma   = (const float*)d_in[14];
    const float* beta    = (const float*)d_in[15];
    const float* head_W  = (const float*)d_in[16];
    const float* head_b  = (const float*)d_in[17];
    const float* trend_W = (const float*)d_in[18];
    const float* trend_b = (const float*)d_in[19];
    float* out = (float*)d_out;
    float* ws  = (float*)d_ws;

    unsigned short* seasB  = (unsigned short*)ws;
    unsigned short* trendB = (unsigned short*)(ws + 688128);
    unsigned short* xpB    = (unsigned short*)(ws + 1376256);
    unsigned short* bufAb  = (unsigned short*)(ws + 2924544);
    unsigned short* tmpB16 = (unsigned short*)(ws + 4988928);
    unsigned short* tmp2   = (unsigned short*)(ws + 7053312);
    unsigned short* bufCb  = (unsigned short*)(ws + 9117696);
    float* qF    = ws + 11182080;
    float* Ore_g = qF;
    float* Oim_g = qF + 2031616;
    float* big   = ws + 15310848;
    unsigned short* hidB = (unsigned short*)big;
    float* Xre_g = big;
    float* Xim_g = big + 2031616;
    unsigned short* WqB = (unsigned short*)(ws + 23568384);
    unsigned short* WoB = (unsigned short*)(ws + 23830528);
    unsigned short* c1B = (unsigned short*)(ws + 24092672);
    unsigned short* c2B = (unsigned short*)(ws + 25141248);
    unsigned short* pWB = (unsigned short*)(ws + 26189824);
    float* cosT = ws + 26288128;
    float* sinT = ws + 26290144;
    float* trendout = ws + 26292160;
    float* parts = ws + 26550208;     // 12 * 258048 floats

    auto cdiv = [](int a, int b) { return (a + b - 1) / b; };

    prep_k<<<5321,256,0,stream>>>(Wq, Wo, c1, c2, WqB, WoB, c1B, c2B, patch_W, pWB, cosT, sinT);
    decomp_input_k<<<cdiv(B_*C_*16,256),256,0,stream>>>(x_enc, seasB, trendB);
    patches_k<<<cdiv(B_*L_*384,256),256,0,stream>>>(seasB, xpB);
    trend_mfma<<<42,256,0,stream>>>(trendB, trend_W, trend_b, head_b, trendout);

    gemm_mfma<<<dim3(4,126),256,0,stream>>>(xpB, pWB, patch_b, (float*)nullptr, bufAb, ML, 512, 384, 0);

    for (int l = 0; l < 2; ++l) {
        const unsigned short* WqB_l = WqB + (size_t)l*512*512;
        const unsigned short* WoB_l = WoB + (size_t)l*512*512;
        const unsigned short* c1B_l = c1B + (size_t)l*FF_*D_;
        const unsigned short* c2B_l = c2B + (size_t)l*D_*FF_;
        const float* bq_l = bq + (size_t)l*512;
        const float* bo_l = bo + (size_t)l*512;
        const float* wr_l = four_wr + (size_t)l*H_*DH_*DH_*MODES_;
        const float* wi_l = four_wi + (size_t)l*H_*DH_*DH_*MODES_;

        gemm_mfma<<<dim3(4,126),256,0,stream>>>(bufAb, WqB_l, bq_l, qF, (unsigned short*)nullptr, ML, 512, 512, 0);
        fourier1_k<<<B_*H_,256,0,stream>>>(qF, cosT, sinT, Xre_g, Xim_g);
        fourier2_k<<<H_*MODES_,256,0,stream>>>(Xre_g, Xim_g, wr_l, wi_l, Ore_g, Oim_g);
        fourier3_k<<<B_*H_,256,0,stream>>>(Ore_g, Oim_g, cosT, sinT, tmpB16);
        gemm_mfma<<<dim3(4,126),256,0,stream>>>(tmpB16, WoB_l, bo_l, (float*)nullptr, tmp2, ML, 512, 512, 0);
        decomp_add_k<<<cdiv(B_*D_,256),256,0,stream>>>(bufAb, tmp2, bufCb);
        gemm_mfma<<<dim3(16,126),256,0,stream>>>(bufCb, c1B_l, (const float*)nullptr, (float*)nullptr, hidB, ML, FF_, 512, 1);
        gemm_mfma<<<dim3(4,126),256,0,stream>>>(hidB, c2B_l, (const float*)nullptr, (float*)nullptr, tmp2, ML, 512, FF_, 0);
        decomp_add_k<<<cdiv(B_*D_,256),256,0,stream>>>(bufCb, tmp2, bufAb);
    }

    ln_colmean_k<<<B_,256,0,stream>>>(bufAb, gamma, beta, tmpB16);
    head_mfma<<<dim3(42,12),256,0,stream>>>(tmpB16, head_W, parts);
    reduce_k<<<cdiv(64512,256),256,0,stream>>>(trendout, parts, out);
}

// Round 11
// 545.765 us; speedup vs baseline: 1.0193x; 1.0176x over previous
//
#include <hip/hip_runtime.h>
#include <math.h>

#define B_ 128
#define T_ 512
#define C_ 21
#define L_ 63
#define D_ 512
#define H_ 8
#define DH_ 64
#define MODES_ 31
#define FF_ 2048
#define P_ 96
#define KMA 25
#define PAD 12
#define NOUT (P_*C_)      /* 2016 */
#define KHEAD (L_*D_)     /* 32256 */
#define ML (B_*L_)        /* 8064 rows */

typedef __attribute__((ext_vector_type(8))) short short8;
typedef __attribute__((ext_vector_type(4))) float f32x4;

__device__ __forceinline__ unsigned short f2b(float f) {
    union { float f; unsigned u; } v; v.f = f;
    unsigned r = v.u + 0x7FFFu + ((v.u >> 16) & 1u);
    return (unsigned short)(r >> 16);
}
__device__ __forceinline__ float b2f(unsigned short u) {
    union { unsigned u; float f; } v; v.u = ((unsigned)u) << 16;
    return v.f;
}
__device__ __forceinline__ void gld_lds16(const void* g, void* l) {
    __builtin_amdgcn_global_load_lds(
        (const __attribute__((address_space(1))) unsigned int*)g,
        (__attribute__((address_space(3))) unsigned int*)l, 16, 0, 0);
}

// ============ prep: all weight conversions + pad + DFT tables, one kernel ============
__global__ void prep_k(const float* __restrict__ Wq, const float* __restrict__ Wo,
                       const float* __restrict__ c1, const float* __restrict__ c2,
                       unsigned short* __restrict__ WqB, unsigned short* __restrict__ WoB,
                       unsigned short* __restrict__ c1B, unsigned short* __restrict__ c2B,
                       const float* __restrict__ pW, unsigned short* __restrict__ pWB,
                       float* __restrict__ cosT, float* __restrict__ sinT) {
    int i = blockIdx.x * 256 + threadIdx.x;
    if (i < 262144) {
        const float* src = (i < 131072) ? Wq : Wo;
        unsigned short* dst = (i < 131072) ? WqB : WoB;
        int j = i & 131071;
        float4 v = ((const float4*)src)[j];
        uint2 p; p.x = (unsigned)f2b(v.x) | ((unsigned)f2b(v.y) << 16);
        p.y = (unsigned)f2b(v.z) | ((unsigned)f2b(v.w) << 16);
        ((uint2*)dst)[j] = p;
    } else if (i < 1310720) {
        int j = i - 262144;
        const float* src = (j < 524288) ? c1 : c2;
        unsigned short* dst = (j < 524288) ? c1B : c2B;
        j &= 524287;
        float4 v = ((const float4*)src)[j];
        uint2 p; p.x = (unsigned)f2b(v.x) | ((unsigned)f2b(v.y) << 16);
        p.y = (unsigned)f2b(v.z) | ((unsigned)f2b(v.w) << 16);
        ((uint2*)dst)[j] = p;
    } else if (i < 1359872) {
        int j = i - 1310720;
        int row = j / 96, c4 = j % 96;
        uint2 p; p.x = 0; p.y = 0;
        if (c4 < 84) {
            float4 v = *(const float4*)(pW + (size_t)row * 336 + c4 * 4);
            p.x = (unsigned)f2b(v.x) | ((unsigned)f2b(v.y) << 16);
            p.y = (unsigned)f2b(v.z) | ((unsigned)f2b(v.w) << 16);
        }
        ((uint2*)pWB)[j] = p;
    } else if (i < 1361888) {
        int j = i - 1359872;
        int m = j / 63, l = j % 63;
        if (m >= MODES_) { cosT[j] = 0.f; sinT[j] = 0.f; }
        else {
            int r = (m * l) % 63;
            double a = 6.283185307179586476925286766559 * (double)r / 63.0;
            cosT[j] = (float)cos(a); sinT[j] = (float)sin(a);
        }
    }
}

// ============ fused series_decomp + patch gather, one block per b ============
__global__ __launch_bounds__(256) void decomp_patches_k(
    const float* __restrict__ x,
    unsigned short* __restrict__ trendB,
    unsigned short* __restrict__ xpB)
{
    __shared__ unsigned short seas[21][512];   // 21.5 KB
    int b = blockIdx.x;
    const float* xb0 = x + (size_t)b * T_ * C_;
    for (int task = threadIdx.x; task < 336; task += 256) {
        int c = task / 16, tc = task % 16;
        const float* xb = xb0 + c;
        int t0 = tc * 32;
        float sum = 0.f;
        #pragma unroll
        for (int i = -PAD; i <= PAD; ++i) {
            int tt = t0 + i; tt = tt < 0 ? 0 : (tt > T_-1 ? T_-1 : tt);
            sum += xb[(size_t)tt * C_];
        }
        for (int t = t0; t < t0 + 32; ++t) {
            float mean = sum * (1.f / KMA);
            float xv = xb[(size_t)t * C_];
            seas[c][t] = f2b(xv - mean);
            trendB[((size_t)b * T_ + t) * C_ + c] = f2b(mean);
            int add = t + 13 > T_-1 ? T_-1 : t + 13;
            int rem = t - 12 < 0 ? 0 : t - 12;
            sum += xb[(size_t)add * C_] - xb[(size_t)rem * C_];
        }
    }
    __syncthreads();
    for (int idx = threadIdx.x; idx < 63*384; idx += 256) {
        int n = idx / 384, col = idx % 384;
        unsigned short v = 0;
        if (col < 336) { int c = col >> 4, j = col & 15; v = seas[c][8*n + j]; }
        xpB[((size_t)b * 63 + n) * 384 + col] = v;
    }
}

// ============ trend head MFMA GEMM, K-split 4: M=2688 (b,c), N=96 (p), K=512 (t) ============
__global__ __launch_bounds__(256) void trend_mfma(
    const unsigned short* __restrict__ trendB, const float* __restrict__ tW,
    const float* __restrict__ tb, const float* __restrict__ hb,
    float* __restrict__ parts)
{
    __shared__ unsigned short Asl[64*32];
    __shared__ unsigned short Wsl[96*32];
    int bm = blockIdx.x, kc = blockIdx.y;
    int t = threadIdx.x, wave = t >> 6, lane = t & 63;
    int wr = wave >> 1, wc = wave & 1, g2 = lane >> 4, rl = lane & 15;
    f32x4 acc[2][3] = {};
    int ar = t >> 2, aslot = t & 3;
    int rowg = bm*64 + ar; int ab = rowg / 21, ac = rowg % 21;
    for (int k0 = kc*128; k0 < kc*128 + 128; k0 += 32) {
        __syncthreads();
        {
            unsigned short vals[8];
            int kb = k0 + aslot*8;
            #pragma unroll
            for (int j = 0; j < 8; ++j)
                vals[j] = trendB[((size_t)ab * T_ + kb + j) * C_ + ac];
            int phys = aslot ^ ((ar>>1)&3);
            *(uint4*)&Asl[ar*32 + phys*8] = *(const uint4*)vals;
        }
        #pragma unroll
        for (int i = 0; i < 3; ++i) {
            int idx = t + 256*i;
            int r = idx >> 3, c4 = idx & 7;
            float4 w4 = *(const float4*)(tW + (size_t)r * T_ + k0 + c4*4);
            uint2 p; p.x = (unsigned)f2b(w4.x) | ((unsigned)f2b(w4.y) << 16);
            p.y = (unsigned)f2b(w4.z) | ((unsigned)f2b(w4.w) << 16);
            *(uint2*)&Wsl[r*32 + (((c4>>1) ^ ((r>>1)&3)) << 3) + ((c4&1) << 2)] = p;
        }
        __syncthreads();
        short8 af[2], wf[3];
        #pragma unroll
        for (int m = 0; m < 2; ++m) {
            int r = wr*32 + m*16 + rl;
            af[m] = *(const short8*)&Asl[r*32 + ((g2 ^ ((r>>1)&3)) << 3)];
        }
        #pragma unroll
        for (int n = 0; n < 3; ++n) {
            int r = wc*48 + n*16 + rl;
            wf[n] = *(const short8*)&Wsl[r*32 + ((g2 ^ ((r>>1)&3)) << 3)];
        }
        #pragma unroll
        for (int m = 0; m < 2; ++m)
            #pragma unroll
            for (int n = 0; n < 3; ++n)
                acc[m][n] = __builtin_amdgcn_mfma_f32_16x16x32_bf16(af[m], wf[n], acc[m][n], 0,0,0);
    }
    float* outT = parts + (size_t)kc * (B_*NOUT);
    #pragma unroll
    for (int n = 0; n < 3; ++n) {
        int p = wc*48 + n*16 + rl;
        #pragma unroll
        for (int m = 0; m < 2; ++m)
            #pragma unroll
            for (int j = 0; j < 4; ++j) {
                int rg = bm*64 + wr*32 + m*16 + g2*4 + j;
                int b = rg / 21, c = rg % 21;
                float v = acc[m][n][j];
                if (kc == 0) v += tb[p] + hb[p*21 + c];
                outT[(size_t)b * NOUT + p*21 + c] = v;
            }
    }
}

// ============ bf16 MFMA GEMM, tile 64(M)x128(N), BK=64, dbuf, optional K-split (blockIdx.z) ============
__global__ __launch_bounds__(256) void gemm_mfma(
    const unsigned short* __restrict__ A,
    const unsigned short* __restrict__ W,
    const float* __restrict__ bias,
    float* __restrict__ Cf,
    unsigned short* __restrict__ Cb,
    int M, int N, int K, int lda, int ldw, int act)
{
    __shared__ unsigned short Asl[2][64*64];
    __shared__ unsigned short Wsl[2][128*64];
    int bm = blockIdx.y, bn = blockIdx.x, kc = blockIdx.z;
    int t = threadIdx.x;
    int wave = t >> 6, lane = t & 63;
    int wr = wave >> 1, wc = wave & 1;
    int g2 = lane >> 4, rl = lane & 15;
    int lr8 = lane >> 3, l7 = lane & 7;
    f32x4 acc[2][4] = {};
    const unsigned short* Ab = A + (size_t)(bm*64) * lda + (size_t)kc * K;
    const unsigned short* Wb = W + (size_t)(bn*128) * ldw + (size_t)kc * K;

    #pragma unroll
    for (int i = 0; i < 2; ++i) {
        int seg = wave*2 + i;
        int r = seg*8 + lr8;
        int ko = (l7 ^ (r & 7)) << 3;
        gld_lds16(Ab + (size_t)r*lda + ko, &Asl[0][seg*512]);
    }
    #pragma unroll
    for (int i = 0; i < 4; ++i) {
        int seg = wave*4 + i;
        int r = seg*8 + lr8;
        int ko = (l7 ^ (r & 7)) << 3;
        gld_lds16(Wb + (size_t)r*ldw + ko, &Wsl[0][seg*512]);
    }

    int cur = 0;
    for (int k0 = 0; k0 < K; k0 += 64, cur ^= 1) {
        __syncthreads();
        if (k0 + 64 < K) {
            int kn = k0 + 64;
            #pragma unroll
            for (int i = 0; i < 2; ++i) {
                int seg = wave*2 + i;
                int r = seg*8 + lr8;
                int ko = (l7 ^ (r & 7)) << 3;
                gld_lds16(Ab + (size_t)r*lda + kn + ko, &Asl[cur^1][seg*512]);
            }
            #pragma unroll
            for (int i = 0; i < 4; ++i) {
                int seg = wave*4 + i;
                int r = seg*8 + lr8;
                int ko = (l7 ^ (r & 7)) << 3;
                gld_lds16(Wb + (size_t)r*ldw + kn + ko, &Wsl[cur^1][seg*512]);
            }
        }
        short8 af[2][2], wf[2][4];
        #pragma unroll
        for (int sub = 0; sub < 2; ++sub) {
            #pragma unroll
            for (int m = 0; m < 2; ++m) {
                int r = wr*32 + m*16 + rl;
                af[sub][m] = *(const short8*)&Asl[cur][r*64 + (((sub*4+g2) ^ (r&7)) << 3)];
            }
            #pragma unroll
            for (int n = 0; n < 4; ++n) {
                int r = wc*64 + n*16 + rl;
                wf[sub][n] = *(const short8*)&Wsl[cur][r*64 + (((sub*4+g2) ^ (r&7)) << 3)];
            }
        }
        #pragma unroll
        for (int sub = 0; sub < 2; ++sub)
            #pragma unroll
            for (int m = 0; m < 2; ++m)
                #pragma unroll
                for (int n = 0; n < 4; ++n)
                    acc[m][n] = __builtin_amdgcn_mfma_f32_16x16x32_bf16(af[sub][m], wf[sub][n], acc[m][n], 0,0,0);
    }

    int crow0 = bm*64 + wr*32;
    int ccol0 = bn*128 + wc*64;
    size_t obase = (size_t)kc * M * N;
    #pragma unroll
    for (int n = 0; n < 4; ++n) {
        int col = ccol0 + n*16 + rl;
        float bv = (bias && kc == 0) ? bias[col] : 0.f;
        #pragma unroll
        for (int m = 0; m < 2; ++m) {
            #pragma unroll
            for (int j = 0; j < 4; ++j) {
                int row = crow0 + m*16 + g2*4 + j;
                float x = acc[m][n][j] + bv;
                if (act == 1) x = 0.5f * x * (1.f + erff(x * 0.70710678118654752f));
                size_t ix = obase + (size_t)row * N + col;
                if (Cf) Cf[ix] = x;
                if (Cb) Cb[ix] = f2b(x);
            }
        }
    }
}

// ============ fourier stage 1: DFT, block per (b,h) ============
__global__ __launch_bounds__(256) void fourier1_k(
    const float* __restrict__ q, const float* __restrict__ cosT, const float* __restrict__ sinT,
    float* __restrict__ Xre_g, float* __restrict__ Xim_g)
{
    __shared__ float qs[63][64];
    __shared__ float ct[2016], st[2016];
    int b = blockIdx.x >> 3, h = blockIdx.x & 7;
    int t = threadIdx.x;
    for (int idx = t; idx < 1008; idx += 256) {
        int l = idx >> 4, e4 = idx & 15;
        *(float4*)&qs[l][e4*4] = *(const float4*)(q + ((size_t)(b*63 + l))*512 + h*64 + e4*4);
    }
    for (int idx = t; idx < 504; idx += 256) {
        *(float4*)&ct[idx*4] = *(const float4*)(cosT + idx*4);
        *(float4*)&st[idx*4] = *(const float4*)(sinT + idx*4);
    }
    __syncthreads();
    int mm = t & 31, g = t >> 5;
    float re[8] = {}, im[8] = {};
    for (int l = 0; l < 63; ++l) {
        float c = ct[mm*63 + l], s = st[mm*63 + l];
        #pragma unroll
        for (int j = 0; j < 8; ++j) {
            float v = qs[l][g*8 + j];
            re[j] = fmaf(v, c, re[j]);
            im[j] = fmaf(-v, s, im[j]);
        }
    }
    if (mm < MODES_) {
        size_t base = ((size_t)(h*MODES_ + mm)*128 + b)*64 + g*8;
        *(float4*)&Xre_g[base]   = *(float4*)&re[0];
        *(float4*)&Xre_g[base+4] = *(float4*)&re[4];
        *(float4*)&Xim_g[base]   = *(float4*)&im[0];
        *(float4*)&Xim_g[base+4] = *(float4*)&im[4];
    }
}

// ============ fourier stage 2: complex mode-mix via bf16 MFMA, block per (h,m) ============
__global__ __launch_bounds__(256) void fourier2_k(
    const float* __restrict__ Xre_g, const float* __restrict__ Xim_g,
    const float* __restrict__ wr, const float* __restrict__ wi,
    float* __restrict__ Ore_g, float* __restrict__ Oim_g)
{
    __shared__ unsigned short Xr[128*64], Xi[128*64];
    __shared__ unsigned short Wr[64*64], Wi[64*64], Wn[64*64];
    int h = blockIdx.x / MODES_, mm = blockIdx.x % MODES_;
    int t = threadIdx.x;
    size_t xbase = ((size_t)(h*MODES_ + mm)) * 128 * 64;
    #pragma unroll
    for (int i = 0; i < 8; ++i) {
        int idx = t + 256*i;
        int r = idx >> 4, c4 = idx & 15;
        int ad = r*64 + (((c4>>1) ^ (r&7)) << 3) + ((c4&1) << 2);
        float4 v = *(const float4*)(Xre_g + xbase + (size_t)r*64 + c4*4);
        uint2 p; p.x = (unsigned)f2b(v.x) | ((unsigned)f2b(v.y) << 16);
        p.y = (unsigned)f2b(v.z) | ((unsigned)f2b(v.w) << 16);
        *(uint2*)&Xr[ad] = p;
        v = *(const float4*)(Xim_g + xbase + (size_t)r*64 + c4*4);
        p.x = (unsigned)f2b(v.x) | ((unsigned)f2b(v.y) << 16);
        p.y = (unsigned)f2b(v.z) | ((unsigned)f2b(v.w) << 16);
        *(uint2*)&Xi[ad] = p;
    }
    #pragma unroll
    for (int i = 0; i < 2; ++i) {
        int idx = t + 256*i;
        int f = idx >> 3, oct = idx & 7;
        unsigned short wrv[8], wiv[8], wnv[8];
        #pragma unroll
        for (int j = 0; j < 8; ++j) {
            int e = oct*8 + j;
            size_t a = (((size_t)(h*64 + e))*64 + f)*MODES_ + mm;
            wrv[j] = f2b(wr[a]);
            wiv[j] = f2b(wi[a]);
            wnv[j] = wiv[j] ^ 0x8000u;
        }
        int ad = f*64 + ((oct ^ (f&7)) << 3);
        *(uint4*)&Wr[ad] = *(const uint4*)wrv;
        *(uint4*)&Wi[ad] = *(const uint4*)wiv;
        *(uint4*)&Wn[ad] = *(const uint4*)wnv;
    }
    __syncthreads();
    int wave = t >> 6, lane = t & 63;
    int wv = wave >> 1, wc = wave & 1;
    int g2 = lane >> 4, rl = lane & 15;
    f32x4 ar[4][2] = {}, ai[4][2] = {};
    #pragma unroll
    for (int sub = 0; sub < 2; ++sub) {
        short8 xr[4], xi[4], br[2], bi[2], bn[2];
        #pragma unroll
        for (int m = 0; m < 4; ++m) {
            int r = wv*64 + m*16 + rl;
            int off = r*64 + (((sub*4+g2) ^ (r&7)) << 3);
            xr[m] = *(const short8*)&Xr[off];
            xi[m] = *(const short8*)&Xi[off];
        }
        #pragma unroll
        for (int n = 0; n < 2; ++n) {
            int r = wc*32 + n*16 + rl;
            int off = r*64 + (((sub*4+g2) ^ (r&7)) << 3);
            br[n] = *(const short8*)&Wr[off];
            bi[n] = *(const short8*)&Wi[off];
            bn[n] = *(const short8*)&Wn[off];
        }
        #pragma unroll
        for (int m = 0; m < 4; ++m)
            #pragma unroll
            for (int n = 0; n < 2; ++n) {
                ar[m][n] = __builtin_amdgcn_mfma_f32_16x16x32_bf16(xr[m], br[n], ar[m][n], 0,0,0);
                ar[m][n] = __builtin_amdgcn_mfma_f32_16x16x32_bf16(xi[m], bn[n], ar[m][n], 0,0,0);
                ai[m][n] = __builtin_amdgcn_mfma_f32_16x16x32_bf16(xr[m], bi[n], ai[m][n], 0,0,0);
                ai[m][n] = __builtin_amdgcn_mfma_f32_16x16x32_bf16(xi[m], br[n], ai[m][n], 0,0,0);
            }
    }
    #pragma unroll
    for (int m = 0; m < 4; ++m)
        #pragma unroll
        for (int n = 0; n < 2; ++n)
            #pragma unroll
            for (int j = 0; j < 4; ++j) {
                int b = wv*64 + m*16 + g2*4 + j;
                int f = wc*32 + n*16 + rl;
                Ore_g[xbase + (size_t)b*64 + f] = ar[m][n][j];
                Oim_g[xbase + (size_t)b*64 + f] = ai[m][n][j];
            }
}

// ============ fourier stage 3: iDFT (drops Im(X0)), block per (b,h), bf16 out ============
__global__ __launch_bounds__(256) void fourier3_k(
    const float* __restrict__ Ore_g, const float* __restrict__ Oim_g,
    const float* __restrict__ cosT, const float* __restrict__ sinT,
    unsigned short* __restrict__ yB)
{
    __shared__ float Ore[31][64], Oim[31][64];
    __shared__ float ct[2016], st[2016];
    int b = blockIdx.x >> 3, h = blockIdx.x & 7;
    int t = threadIdx.x;
    for (int idx = t; idx < 496; idx += 256) {
        int m = idx >> 4, e4 = idx & 15;
        size_t a = ((size_t)(h*MODES_ + m)*128 + b)*64 + e4*4;
        *(float4*)&Ore[m][e4*4] = *(const float4*)(Ore_g + a);
        *(float4*)&Oim[m][e4*4] = *(const float4*)(Oim_g + a);
    }
    for (int idx = t; idx < 504; idx += 256) {
        *(float4*)&ct[idx*4] = *(const float4*)(cosT + idx*4);
        *(float4*)&st[idx*4] = *(const float4*)(sinT + idx*4);
    }
    __syncthreads();
    int f = t & 63, w = t >> 6;
    int l0 = w*16;
    float y[16];
    float r0 = Ore[0][f];
    #pragma unroll
    for (int i = 0; i < 16; ++i) y[i] = r0;
    for (int m = 1; m < MODES_; ++m) {
        float re2 = 2.f*Ore[m][f], im2 = 2.f*Oim[m][f];
        #pragma unroll
        for (int i = 0; i < 16; ++i) {
            y[i] = fmaf(re2, ct[m*63 + l0 + i], y[i]);
            y[i] = fmaf(-im2, st[m*63 + l0 + i], y[i]);
        }
    }
    int nl = (w == 3) ? 15 : 16;
    unsigned short* yo = yB + ((size_t)(b*512) + h*64 + f) * 63 + l0;
    for (int i = 0; i < nl; ++i) yo[i] = f2b(y[i] * (1.f/63.f));
}

// ============ (X+Y1+Y2) - movavg(X+Y1+Y2), bf16, load-once register window ============
__global__ void decomp_add_k(const unsigned short* __restrict__ X,
                             const unsigned short* __restrict__ Y1,
                             const unsigned short* __restrict__ Y2,
                             unsigned short* __restrict__ outB) {
    int idx = blockIdx.x * 256 + threadIdx.x;
    if (idx >= B_*D_) return;
    int b = idx >> 9, d = idx & 511;
    const unsigned short* xp = X  + (size_t)b * L_ * D_ + d;
    const unsigned short* y1 = Y1 + (size_t)b * L_ * D_ + d;
    const unsigned short* y2 = Y2 + (size_t)b * L_ * D_ + d;
    unsigned short* ob = outB + (size_t)b * L_ * D_ + d;
    float v[63];
    #pragma unroll
    for (int l = 0; l < 63; ++l)
        v[l] = b2f(xp[(size_t)l*D_]) + b2f(y1[(size_t)l*D_]) + b2f(y2[(size_t)l*D_]);
    float sum = 13.f * v[0];
    #pragma unroll
    for (int j = 1; j <= 12; ++j) sum += v[j];
    #pragma unroll
    for (int l = 0; l < 63; ++l) {
        ob[(size_t)l*D_] = f2b(v[l] - sum * (1.f / KMA));
        int add = l + 13 > 62 ? 62 : l + 13;
        int rem = l - 12 < 0 ? 0 : l - 12;
        sum += v[add] - v[rem];
    }
}

// ============ fused layernorm (row) + mean-subtract (column over L), block per b ============
__global__ __launch_bounds__(256) void ln_colmean_k(
    const unsigned short* __restrict__ Xb, const float* __restrict__ g,
    const float* __restrict__ bt, unsigned short* __restrict__ outB)
{
    __shared__ unsigned short lds[63][512];
    int b = blockIdx.x;
    int w = threadIdx.x >> 6, lane = threadIdx.x & 63;
    for (int i = 0; i < 16; ++i) {
        int row = w*16 + i;
        if (row >= 63) break;
        const unsigned short* x = Xb + ((size_t)(b*63 + row))*512 + lane*8;
        uint4 raw = *(const uint4*)x;
        const unsigned short* rp = (const unsigned short*)&raw;
        float v[8]; float s = 0.f, s2 = 0.f;
        #pragma unroll
        for (int j = 0; j < 8; ++j) { v[j] = b2f(rp[j]); s += v[j]; s2 += v[j]*v[j]; }
        #pragma unroll
        for (int o = 32; o > 0; o >>= 1) { s += __shfl_down(s, o); s2 += __shfl_down(s2, o); }
        s = __shfl(s, 0); s2 = __shfl(s2, 0);
        float mu = s * (1.f/D_);
        float var = s2 * (1.f/D_) - mu*mu;
        float rs = rsqrtf(var + 1e-5f);
        unsigned short o16[8];
        #pragma unroll
        for (int j = 0; j < 8; ++j) {
            int d = lane*8 + j;
            o16[j] = f2b((v[j] - mu) * rs * g[d] + bt[d]);
        }
        *(uint4*)&lds[row][lane*8] = *(const uint4*)o16;
    }
    __syncthreads();
    #pragma unroll
    for (int i = 0; i < 2; ++i) {
        int d = threadIdx.x + 256*i;
        float s = 0.f;
        for (int l = 0; l < 63; ++l) s += b2f(lds[l][d]);
        s *= (1.f / 63.f);
        for (int l = 0; l < 63; ++l)
            outB[((size_t)(b*63 + l))*512 + d] = f2b(b2f(lds[l][d]) - s);
    }
}

// ============ head GEMM: barrier-free K-loop, W direct-to-register ============
__global__ __launch_bounds__(256) void head_mfma(
    const unsigned short* __restrict__ A,
    const float* __restrict__ W,
    float* __restrict__ parts)
{
    __shared__ float red[128][48];
    int nt = blockIdx.x;
    int kc = blockIdx.y;
    int wv = threadIdx.x >> 6, lane = threadIdx.x & 63;
    int rl = lane & 15, g2 = lane >> 4;
    f32x4 acc[8][3] = {};
    const unsigned short* Ab = A + (size_t)rl * KHEAD;
    const float* Wb = W + (size_t)(nt*48 + rl) * KHEAD;
    int kbeg = kc*2688 + wv*672 + g2*8;

    for (int ks = 0; ks < 21; ++ks) {
        int k = kbeg + ks*32;
        short8 af[8];
        #pragma unroll
        for (int m = 0; m < 8; ++m)
            af[m] = *(const short8*)(Ab + (size_t)(m*16) * KHEAD + k);
        short8 wf[3];
        #pragma unroll
        for (int n = 0; n < 3; ++n) {
            float4 lo = *(const float4*)(Wb + (size_t)(n*16) * KHEAD + k);
            float4 hi = *(const float4*)(Wb + (size_t)(n*16) * KHEAD + k + 4);
            unsigned short u[8] = { f2b(lo.x), f2b(lo.y), f2b(lo.z), f2b(lo.w),
                                    f2b(hi.x), f2b(hi.y), f2b(hi.z), f2b(hi.w) };
            wf[n] = *(const short8*)u;
        }
        #pragma unroll
        for (int m = 0; m < 8; ++m)
            #pragma unroll
            for (int n = 0; n < 3; ++n)
                acc[m][n] = __builtin_amdgcn_mfma_f32_16x16x32_bf16(af[m], wf[n], acc[m][n], 0,0,0);
    }

    for (int w = 0; w < 4; ++w) {
        if (wv == w) {
            #pragma unroll
            for (int m = 0; m < 8; ++m)
                #pragma unroll
                for (int n = 0; n < 3; ++n)
                    #pragma unroll
                    for (int j = 0; j < 4; ++j) {
                        int row = m*16 + g2*4 + j, col = n*16 + rl;
                        if (w == 0) red[row][col] = acc[m][n][j];
                        else        red[row][col] += acc[m][n][j];
                    }
        }
        __syncthreads();
    }
    float* pout = parts + (size_t)(4 + kc) * (B_*NOUT);
    for (int idx = threadIdx.x; idx < 128*48; idx += 256) {
        int row = idx / 48, col = idx % 48;
        pout[(size_t)row * NOUT + nt*48 + col] = red[row][col];
    }
}

// ============ out = sum of 16 parts (4 trend + 12 head) ============
__global__ void reduce_k(const float* __restrict__ parts, float* __restrict__ out) {
    int i = blockIdx.x * 256 + threadIdx.x;
    if (i >= 64512) return;
    float4 s = {0.f, 0.f, 0.f, 0.f};
    for (int kc = 0; kc < 16; ++kc) {
        float4 p = ((const float4*)parts)[(size_t)kc * 64512 + i];
        s.x += p.x; s.y += p.y; s.z += p.z; s.w += p.w;
    }
    ((float4*)out)[i] = s;
}

extern "C" void kernel_launch(void* const* d_in, const int* in_sizes, int n_in,
                              void* d_out, int out_size, void* d_ws, size_t ws_size,
                              hipStream_t stream) {
    const float* x_enc   = (const float*)d_in[0];
    const float* patch_W = (const float*)d_in[4];
    const float* patch_b = (const float*)d_in[5];
    const float* Wq      = (const float*)d_in[6];
    const float* bq      = (const float*)d_in[7];
    const float* Wo      = (const float*)d_in[8];
    const float* bo      = (const float*)d_in[9];
    const float* four_wr = (const float*)d_in[10];
    const float* four_wi = (const float*)d_in[11];
    const float* c1      = (const float*)d_in[12];
    const float* c2      = (const float*)d_in[13];
    const float* gamma   = (const float*)d_in[14];
    const float* beta    = (const float*)d_in[15];
    const float* head_W  = (const float*)d_in[16];
    const float* head_b  = (const float*)d_in[17];
    const float* trend_W = (const float*)d_in[18];
    const float* trend_b = (const float*)d_in[19];
    float* out = (float*)d_out;
    float* ws  = (float*)d_ws;

    // -------- workspace layout (float-offset units), exact extents with gaps --------
    // trendB:   0        .. 688,128      (1,376,256 u16)
    unsigned short* trendB = (unsigned short*)ws;
    // xpB:      700,000  .. 2,248,288    (8064x384 u16)
    unsigned short* xpB    = (unsigned short*)(ws + 700000);
    // bufAb:    2,300,000 .. 4,364,384   (8064x512 u16)
    unsigned short* bufAb  = (unsigned short*)(ws + 2300000);
    // tmpB16:   4,400,000 .. 6,464,384
    unsigned short* tmpB16 = (unsigned short*)(ws + 4400000);
    // tmp2:     6,500,000 .. 10,628,768  (2 x 8064x512 u16)
    unsigned short* tmp2   = (unsigned short*)(ws + 6500000);
    // bufCb:    10,700,000 .. 12,764,384
    unsigned short* bufCb  = (unsigned short*)(ws + 10700000);
    // qF:       12,800,000 .. 16,928,768 (8064x512 f32; also Ore/Oim 2x2,031,616)
    float* qF    = ws + 12800000;
    float* Ore_g = qF;
    float* Oim_g = qF + 2031616;
    // big:      17,000,000 .. 25,257,536 (hidB 8064x2048 u16 / Xre+Xim 2x2,031,616 f32)
    float* big   = ws + 17000000;
    unsigned short* hidB = (unsigned short*)big;
    float* Xre_g = big;
    float* Xim_g = big + 2031616;
    // WqB: 25,300,000 (+262,144)  WoB: 25,600,000 (+262,144)
    unsigned short* WqB = (unsigned short*)(ws + 25300000);
    unsigned short* WoB = (unsigned short*)(ws + 25600000);
    // c1B: 25,900,000 (+1,048,576)  c2B: 27,000,000 (+1,048,576)
    unsigned short* c1B = (unsigned short*)(ws + 25900000);
    unsigned short* c2B = (unsigned short*)(ws + 27000000);
    // pWB: 28,100,000 (+98,304)
    unsigned short* pWB = (unsigned short*)(ws + 28100000);
    float* cosT  = ws + 28200000;
    float* sinT  = ws + 28210000;
    // parts: 28,250,000 .. 32,378,768 (16 x 258,048 f32)
    float* parts = ws + 28250000;

    auto cdiv = [](int a, int b) { return (a + b - 1) / b; };

    prep_k<<<5321,256,0,stream>>>(Wq, Wo, c1, c2, WqB, WoB, c1B, c2B, patch_W, pWB, cosT, sinT);
    decomp_patches_k<<<B_,256,0,stream>>>(x_enc, trendB, xpB);
    trend_mfma<<<dim3(42,4),256,0,stream>>>(trendB, trend_W, trend_b, head_b, parts);

    gemm_mfma<<<dim3(4,126,1),256,0,stream>>>(xpB, pWB, patch_b, (float*)nullptr, bufAb,
                                              ML, 512, 384, 384, 384, 0);

    for (int l = 0; l < 2; ++l) {
        const unsigned short* WqB_l = WqB + (size_t)l*512*512;
        const unsigned short* WoB_l = WoB + (size_t)l*512*512;
        const unsigned short* c1B_l = c1B + (size_t)l*FF_*D_;
        const unsigned short* c2B_l = c2B + (size_t)l*D_*FF_;
        const float* bq_l = bq + (size_t)l*512;
        const float* bo_l = bo + (size_t)l*512;
        const float* wr_l = four_wr + (size_t)l*H_*DH_*DH_*MODES_;
        const float* wi_l = four_wi + (size_t)l*H_*DH_*DH_*MODES_;

        gemm_mfma<<<dim3(4,126,1),256,0,stream>>>(bufAb, WqB_l, bq_l, qF, (unsigned short*)nullptr,
                                                  ML, 512, 512, 512, 512, 0);
        fourier1_k<<<B_*H_,256,0,stream>>>(qF, cosT, sinT, Xre_g, Xim_g);
        fourier2_k<<<H_*MODES_,256,0,stream>>>(Xre_g, Xim_g, wr_l, wi_l, Ore_g, Oim_g);
        fourier3_k<<<B_*H_,256,0,stream>>>(Ore_g, Oim_g, cosT, sinT, tmpB16);
        // Wo: K=512 split into 2x256; bf16 partials in tmp2[0], tmp2[1]
        gemm_mfma<<<dim3(4,126,2),256,0,stream>>>(tmpB16, WoB_l, bo_l, (float*)nullptr, tmp2,
                                                  ML, 512, 256, 512, 512, 0);
        decomp_add_k<<<cdiv(B_*D_,256),256,0,stream>>>(bufAb, tmp2, tmp2 + (size_t)ML*512, bufCb);
        gemm_mfma<<<dim3(16,126,1),256,0,stream>>>(bufCb, c1B_l, (const float*)nullptr, (float*)nullptr, hidB,
                                                   ML, FF_, 512, 512, 512, 1);
        // c2: K=2048 split into 2x1024; bf16 partials in tmp2[0], tmp2[1]
        gemm_mfma<<<dim3(4,126,2),256,0,stream>>>(hidB, c2B_l, (const float*)nullptr, (float*)nullptr, tmp2,
                                                  ML, 512, 1024, 2048, 2048, 0);
        decomp_add_k<<<cdiv(B_*D_,256),256,0,stream>>>(bufCb, tmp2, tmp2 + (size_t)ML*512, bufAb);
    }

    ln_colmean_k<<<B_,256,0,stream>>>(bufAb, gamma, beta, tmpB16);
    head_mfma<<<dim3(42,12),256,0,stream>>>(tmpB16, head_W, parts);
    reduce_k<<<cdiv(64512,256),256,0,stream>>>(parts, out);
}